// Round 3
// baseline (941.635 us; speedup 1.0000x reference)
//
#include <hip/hip_runtime.h>
#include <math.h>

#define NE   8192
#define ED   512
#define BB   8
#define TT   1024
#define MM   (BB*TT)

#define FLT_BIG 3.402823466e38f
#define MARGIN  0.5f

typedef _Float16 half8 __attribute__((ext_vector_type(8)));
typedef _Float16 half4 __attribute__((ext_vector_type(4)));
typedef float    floatx4 __attribute__((ext_vector_type(4)));

typedef __attribute__((address_space(3))) unsigned int       lds_u32;
typedef const __attribute__((address_space(1))) unsigned int gbl_u32;

__device__ __forceinline__ void async_copy16(void* lds, const void* g) {
    __builtin_amdgcn_global_load_lds((gbl_u32*)(unsigned long long)g,
                                     (lds_u32*)(unsigned long long)lds,
                                     16, 0, 0);
}

// ---------------------------------------------------------------------------
// K0: z (B,C,T) fp32 -> Zh[m][512] = f16(4z), m = b*T + t. 64x64 transpose.
// ---------------------------------------------------------------------------
__global__ __launch_bounds__(256) void k_prep_z(
    const float* __restrict__ z, _Float16* __restrict__ Zh)
{
    __shared__ float T[64][65];
    const int ct = blockIdx.x, tt = blockIdx.y, b = blockIdx.z;
    const int tid = threadIdx.x;
    const int f4 = tid & 15;
    const int c0 = tid >> 4;
#pragma unroll
    for (int r = 0; r < 4; ++r) {
        const int c = c0 + r * 16;
        const float4 v = *(const float4*)(z + ((size_t)(b * ED + ct * 64 + c)) * TT + tt * 64 + f4 * 4);
        T[f4*4+0][c] = v.x; T[f4*4+1][c] = v.y;
        T[f4*4+2][c] = v.z; T[f4*4+3][c] = v.w;
    }
    __syncthreads();
    const int tl = tid >> 2, q = tid & 3;
    const size_t m = (size_t)b * TT + tt * 64 + tl;
    _Float16* outh = Zh + m * 512 + ct * 64 + q * 16;
#pragma unroll
    for (int g = 0; g < 2; ++g) {
        half8 hv;
#pragma unroll
        for (int jj = 0; jj < 8; ++jj)
            hv[jj] = (_Float16)(4.0f * T[tl][q*16 + g*8 + jj]);
        *(half8*)(outh + g * 8) = hv;
    }
}

// ---------------------------------------------------------------------------
// K0b: generic fp32 [rows][512] -> f16 hi/lo [rows][1024] at 64x scale.
// grid = rows/2 blocks of 256 (each lane: one float4 group).
// ---------------------------------------------------------------------------
__global__ __launch_bounds__(256) void k_prep_hl(
    const float* __restrict__ src, _Float16* __restrict__ dst)
{
    const int g = blockIdx.x * 256 + threadIdx.x;
    const int row = g >> 7, c4 = (g & 127) * 4;
    const float4 v = *(const float4*)(src + (size_t)row * 512 + c4);
    half4 h, l;
    const float s[4] = {v.x * 64.0f, v.y * 64.0f, v.z * 64.0f, v.w * 64.0f};
#pragma unroll
    for (int j = 0; j < 4; ++j) {
        const _Float16 hh = (_Float16)s[j];
        h[j] = hh;
        l[j] = (_Float16)(s[j] - (float)hh);
    }
    *(half4*)(dst + (size_t)row * 1024 + c4) = h;
    *(half4*)(dst + (size_t)row * 1024 + 512 + c4) = l;
}

// ---------------------------------------------------------------------------
// K1: codebook GEMM via 3-term hi/lo f16 MFMA (fp32-grade accuracy ~1e-6):
// cb[n][d] = (eh.ph + eh.pl + el.ph)/4096 + pb[d]; Ch = f16(64*cb); cnorm.
// Tile 128x128, grid (64, 4).
// ---------------------------------------------------------------------------
__global__ __launch_bounds__(256) void k_cb(
    const _Float16* __restrict__ Eb, const _Float16* __restrict__ Wb,
    const float* __restrict__ pb, float* __restrict__ cb,
    _Float16* __restrict__ Ch, float* __restrict__ cnorm)
{
    __shared__ __align__(16) _Float16 As[128 * 64];
    __shared__ __align__(16) _Float16 Bs[128 * 64];

    const int tid = threadIdx.x;
    const int wave = tid >> 6, lane = tid & 63;
    const int n0 = blockIdx.x * 128, d0 = blockIdx.y * 128;
    const int wm = wave >> 1, wn = wave & 1;
    const int lm = lane & 15, lq = lane >> 4;

    floatx4 acc[4][4];
#pragma unroll
    for (int i = 0; i < 4; ++i)
#pragma unroll
        for (int j = 0; j < 4; ++j) acc[i][j] = (floatx4)0.0f;

    for (int lc = 0; lc < 24; ++lc) {
        const int kA = (lc < 8) ? lc * 64 : (lc < 16 ? (lc - 8) * 64 : 512 + (lc - 16) * 64);
        const int kB = (lc < 8) ? lc * 64 : (lc < 16 ? 512 + (lc - 8) * 64 : (lc - 16) * 64);

        __syncthreads();
#pragma unroll
        for (int r = 0; r < 4; ++r) {
            const int s = wave * 4 + r;
            const int row = s * 8 + (lane >> 3);
            const int src = (lane & 7) ^ (row & 7);
            async_copy16(&As[s * 512], Eb + (size_t)(n0 + row) * 1024 + kA + src * 8);
            async_copy16(&Bs[s * 512], Wb + (size_t)(d0 + row) * 1024 + kB + src * 8);
        }
        __syncthreads();

#pragma unroll
        for (int ks = 0; ks < 2; ++ks) {
            half8 af[4], bf[4];
#pragma unroll
            for (int i = 0; i < 4; ++i) {
                const int row = wm * 64 + i * 16 + lm;
                const int slot = (ks * 4 + lq) ^ (row & 7);
                af[i] = *(const half8*)&As[row * 64 + slot * 8];
            }
#pragma unroll
            for (int j = 0; j < 4; ++j) {
                const int row = wn * 64 + j * 16 + lm;
                const int slot = (ks * 4 + lq) ^ (row & 7);
                bf[j] = *(const half8*)&Bs[row * 64 + slot * 8];
            }
#pragma unroll
            for (int i = 0; i < 4; ++i)
#pragma unroll
                for (int j = 0; j < 4; ++j)
                    acc[i][j] = __builtin_amdgcn_mfma_f32_16x16x32_f16(af[i], bf[j], acc[i][j], 0, 0, 0);
        }
    }

    float bias[4];
#pragma unroll
    for (int j = 0; j < 4; ++j) bias[j] = pb[d0 + wn * 64 + j * 16 + lm];

    float nsum[16];
#pragma unroll
    for (int p = 0; p < 16; ++p) nsum[p] = 0.0f;

#pragma unroll
    for (int i = 0; i < 4; ++i) {
#pragma unroll
        for (int j = 0; j < 4; ++j) {
            const int d = d0 + wn * 64 + j * 16 + lm;
#pragma unroll
            for (int r = 0; r < 4; ++r) {
                const float v = acc[i][j][r] * 0.000244140625f + bias[j];  // 1/4096
                const int n = n0 + wm * 64 + i * 16 + lq * 4 + r;
                cb[(size_t)n * 512 + d] = v;
                Ch[(size_t)n * 512 + d] = (_Float16)(v * 64.0f);
                nsum[i * 4 + r] += v * v;
            }
        }
    }
#pragma unroll
    for (int stp = 1; stp < 16; stp <<= 1) {
#pragma unroll
        for (int p = 0; p < 16; ++p) nsum[p] += __shfl_xor(nsum[p], stp);
    }
    float myv = nsum[0];
#pragma unroll
    for (int p = 1; p < 16; ++p) if (lm == p) myv = nsum[p];
    const int n = n0 + wm * 64 + (lm >> 2) * 16 + lq * 4 + (lm & 3);
    atomicAdd(&cnorm[n], myv);
}

// ---------------------------------------------------------------------------
// K2: coarse distance GEMM (hi-only, K=512). f = cnorm[n] - zh.ch/128.
// Writes per-(row, 64-code unit) min into bmin[m][128]. No atomics.
// ---------------------------------------------------------------------------
__global__ __launch_bounds__(256) void k_coarse(
    const _Float16* __restrict__ Zh, const _Float16* __restrict__ Ch,
    const float* __restrict__ cnorm, const int* __restrict__ dom_arr,
    float* __restrict__ bmin)
{
    const int mt = blockIdx.x;          // 0..63
    const int nt = blockIdx.y;          // 0..63
    const int b = mt >> 3;
    const int dom = dom_arr[b];
    const int chunk = nt >> 4;
    const bool valid = (dom == 3) || (dom == 0 && chunk == 0) ||
                       (dom == 1 && chunk == 1) || (dom == 2 && chunk >= 2);
    if (!valid) return;

    __shared__ __align__(16) _Float16 As[128 * 64];
    __shared__ __align__(16) _Float16 Bs[128 * 64];

    const int tid = threadIdx.x;
    const int wave = tid >> 6, lane = tid & 63;
    const int m0 = mt * 128, n0 = nt * 128;
    const int wm = wave >> 1, wn = wave & 1;
    const int lm = lane & 15, lq = lane >> 4;

    floatx4 acc[4][4];
#pragma unroll
    for (int i = 0; i < 4; ++i)
#pragma unroll
        for (int j = 0; j < 4; ++j) acc[i][j] = (floatx4)0.0f;

    for (int lc = 0; lc < 8; ++lc) {
        const int kk0 = lc * 64;
        __syncthreads();
#pragma unroll
        for (int r = 0; r < 4; ++r) {
            const int s = wave * 4 + r;
            const int row = s * 8 + (lane >> 3);
            const int src = (lane & 7) ^ (row & 7);
            async_copy16(&As[s * 512], Zh + (size_t)(m0 + row) * 512 + kk0 + src * 8);
            async_copy16(&Bs[s * 512], Ch + (size_t)(n0 + row) * 512 + kk0 + src * 8);
        }
        __syncthreads();

#pragma unroll
        for (int ks = 0; ks < 2; ++ks) {
            half8 af[4], bf[4];
#pragma unroll
            for (int i = 0; i < 4; ++i) {
                const int row = wm * 64 + i * 16 + lm;
                const int slot = (ks * 4 + lq) ^ (row & 7);
                af[i] = *(const half8*)&As[row * 64 + slot * 8];
            }
#pragma unroll
            for (int j = 0; j < 4; ++j) {
                const int row = wn * 64 + j * 16 + lm;
                const int slot = (ks * 4 + lq) ^ (row & 7);
                bf[j] = *(const half8*)&Bs[row * 64 + slot * 8];
            }
#pragma unroll
            for (int i = 0; i < 4; ++i)
#pragma unroll
                for (int j = 0; j < 4; ++j)
                    acc[i][j] = __builtin_amdgcn_mfma_f32_16x16x32_f16(af[i], bf[j], acc[i][j], 0, 0, 0);
        }
    }

    float bv[16];
#pragma unroll
    for (int p = 0; p < 16; ++p) bv[p] = FLT_BIG;

#pragma unroll
    for (int j = 0; j < 4; ++j) {
        const float cn = cnorm[n0 + wn * 64 + j * 16 + lm];
#pragma unroll
        for (int i = 0; i < 4; ++i) {
#pragma unroll
            for (int r = 0; r < 4; ++r) {
                const float f = cn - acc[i][j][r] * 0.0078125f;   // 1/128
                const int p = i * 4 + r;
                bv[p] = fminf(bv[p], f);
            }
        }
    }
#pragma unroll
    for (int stp = 1; stp < 16; stp <<= 1) {
#pragma unroll
        for (int p = 0; p < 16; ++p) bv[p] = fminf(bv[p], __shfl_xor(bv[p], stp));
    }
    float myv = bv[0];
#pragma unroll
    for (int p = 1; p < 16; ++p) if (lm == p) myv = bv[p];
    const int m = m0 + wm * 64 + (lm >> 2) * 16 + lq * 4 + (lm & 3);
    bmin[(size_t)m * 128 + nt * 2 + wn] = myv;
}

// ---------------------------------------------------------------------------
// K3: refine. One wave per z-row: gmin over 128 unit-minima, then exact fp32
// distances for units within MARGIN; argmin (ascending scan -> first min).
// ---------------------------------------------------------------------------
__global__ __launch_bounds__(256) void k_refine(
    const float* __restrict__ z, const float* __restrict__ cb,
    const float* __restrict__ cnorm, const float* __restrict__ bmin,
    int* __restrict__ minidx, float* __restrict__ out_idx)
{
    const int m = blockIdx.x * 4 + (threadIdx.x >> 6);
    const int lane = threadIdx.x & 63;
    const int b = m >> 10, t = m & 1023;

    float zr[8];
#pragma unroll
    for (int j = 0; j < 8; ++j)
        zr[j] = z[((size_t)(b * ED + lane + 64 * j)) * TT + t];

    const float bm0 = bmin[(size_t)m * 128 + lane * 2];
    const float bm1 = bmin[(size_t)m * 128 + lane * 2 + 1];
    float g = fminf(bm0, bm1);
#pragma unroll
    for (int s = 32; s > 0; s >>= 1) g = fminf(g, __shfl_xor(g, s));
    const float thr = g + MARGIN;

    float bestv = FLT_BIG; int besti = 0;
    for (int u = 0; u < 128; ++u) {
        const float uv = __shfl((u & 1) ? bm1 : bm0, u >> 1);
        if (uv > thr) continue;
        const int nbase = u * 64;
        for (int q = 0; q < 64; q += 2) {
            const float* r0 = cb + (size_t)(nbase + q) * 512 + lane;
            const float* r1 = r0 + 512;
            float d0 = 0.f, d1 = 0.f;
#pragma unroll
            for (int j = 0; j < 8; ++j) {
                d0 += zr[j] * r0[64 * j];
                d1 += zr[j] * r1[64 * j];
            }
#pragma unroll
            for (int s = 32; s > 0; s >>= 1) {
                d0 += __shfl_xor(d0, s);
                d1 += __shfl_xor(d1, s);
            }
            const float f0 = cnorm[nbase + q]     - 2.0f * d0;
            const float f1 = cnorm[nbase + q + 1] - 2.0f * d1;
            if (f0 < bestv) { bestv = f0; besti = nbase + q; }
            if (f1 < bestv) { bestv = f1; besti = nbase + q + 1; }
        }
    }
    if (lane == 0) {
        minidx[m] = besti;
        out_idx[m] = (float)besti;
    }
}

// ---------------------------------------------------------------------------
// K4: z_q gather (fp32 codebook) + transpose to (B,C,T) + commit loss.
// ---------------------------------------------------------------------------
__global__ __launch_bounds__(256) void k_zq(
    const float* __restrict__ z, const float* __restrict__ cb,
    const int* __restrict__ minidx, float* __restrict__ outz,
    float* __restrict__ lossacc)
{
    __shared__ float red[4];
    const int blk = blockIdx.x;
    const int b = blk >> 4;
    const int t0 = (blk & 15) * 64;
    const int tl = threadIdx.x & 63;
    const int cg = threadIdx.x >> 6;
    const int t = t0 + tl;
    const int idx = minidx[b * TT + t];
    const float* __restrict__ crow = cb + (size_t)idx * 512;

    float lsum = 0.f;
    for (int c = cg; c < ED; c += 4) {
        const float cv = crow[c];
        const size_t off = ((size_t)(b * ED + c)) * TT + t;
        const float zv = z[off];
        const float d = cv - zv;
        lsum += d * d;
        outz[off] = cv;
    }
#pragma unroll
    for (int off = 32; off > 0; off >>= 1) lsum += __shfl_down(lsum, off);
    if (tl == 0) red[threadIdx.x >> 6] = lsum;
    __syncthreads();
    if (threadIdx.x == 0)
        atomicAdd(lossacc, red[0] + red[1] + red[2] + red[3]);
}

__global__ void k_final(const float* __restrict__ lossacc, float* __restrict__ outloss)
{
    *outloss = 1.25f * (*lossacc) / (float)(BB * ED * TT);
}

// ---------------------------------------------------------------------------
extern "C" void kernel_launch(void* const* d_in, const int* in_sizes, int n_in,
                              void* d_out, int out_size, void* d_ws, size_t ws_size,
                              hipStream_t stream)
{
    const float* z   = (const float*)d_in[0];
    const int*   dom = (const int*)d_in[1];
    const float* emb = (const float*)d_in[3];
    const float* pw  = (const float*)d_in[4];
    const float* pb  = (const float*)d_in[5];
    float* out = (float*)d_out;

    // workspace layout
    char* p = (char*)d_ws;
    _Float16* Zh = (_Float16*)p;            p += (size_t)MM * 512 * 2;   // 8 MB
    _Float16* Eb = (_Float16*)p;            p += (size_t)NE * 1024 * 2;  // 16 MB
    _Float16* Wb = (_Float16*)p;            p += (size_t)ED * 1024 * 2;  // 1 MB
    float*    cb = (float*)p;               p += (size_t)NE * 512 * 4;   // 16 MB
    _Float16* Ch = (_Float16*)p;            p += (size_t)NE * 512 * 2;   // 8 MB
    float* cnorm = (float*)p;               p += (size_t)NE * 4;
    float* bmin  = (float*)p;               p += (size_t)MM * 128 * 4;   // 4 MB
    int*   minidx = (int*)p;                p += (size_t)MM * 4;
    float* lossacc = (float*)p;

    hipMemsetAsync(cnorm, 0, NE * sizeof(float), stream);
    hipMemsetAsync(bmin, 0x7F, (size_t)MM * 128 * sizeof(float), stream); // ~3.4e38
    hipMemsetAsync(lossacc, 0, sizeof(float), stream);

    k_prep_z <<<dim3(8, 16, 8), 256, 0, stream>>>(z, Zh);
    k_prep_hl<<<NE / 2, 256, 0, stream>>>(emb, Eb);
    k_prep_hl<<<ED / 2, 256, 0, stream>>>(pw, Wb);
    k_cb     <<<dim3(64, 4), 256, 0, stream>>>(Eb, Wb, pb, cb, Ch, cnorm);
    k_coarse <<<dim3(64, 64), 256, 0, stream>>>(Zh, Ch, cnorm, dom, bmin);
    k_refine <<<MM / 4, 256, 0, stream>>>(z, cb, cnorm, bmin, minidx, out + (size_t)NE * ED);
    k_zq     <<<128, 256, 0, stream>>>(z, cb, minidx, out, lossacc);
    k_final  <<<1, 1, 0, stream>>>(lossacc, out + (size_t)NE * ED + MM);
}

// Round 4
// 340.785 us; speedup vs baseline: 2.7631x; 2.7631x over previous
//
#include <hip/hip_runtime.h>
#include <math.h>

#define NE   8192
#define ED   512
#define BB   8
#define TT   1024
#define MM   (BB*TT)

#define FLT_BIG 3.402823466e38f
#define MARGIN  0.08f

typedef _Float16 half8 __attribute__((ext_vector_type(8)));
typedef _Float16 half4 __attribute__((ext_vector_type(4)));
typedef float    floatx4 __attribute__((ext_vector_type(4)));

typedef __attribute__((address_space(3))) unsigned int       lds_u32;
typedef const __attribute__((address_space(1))) unsigned int gbl_u32;

__device__ __forceinline__ void async_copy16(void* lds, const void* g) {
    __builtin_amdgcn_global_load_lds((gbl_u32*)(unsigned long long)g,
                                     (lds_u32*)(unsigned long long)lds,
                                     16, 0, 0);
}

// ---------------------------------------------------------------------------
// K0: z (B,C,T) fp32 -> Zh[m][512] = f16(4z), m = b*T + t. 64x64 transpose.
// ---------------------------------------------------------------------------
__global__ __launch_bounds__(256) void k_prep_z(
    const float* __restrict__ z, _Float16* __restrict__ Zh)
{
    __shared__ float T[64][65];
    const int ct = blockIdx.x, tt = blockIdx.y, b = blockIdx.z;
    const int tid = threadIdx.x;
    const int f4 = tid & 15;
    const int c0 = tid >> 4;
#pragma unroll
    for (int r = 0; r < 4; ++r) {
        const int c = c0 + r * 16;
        const float4 v = *(const float4*)(z + ((size_t)(b * ED + ct * 64 + c)) * TT + tt * 64 + f4 * 4);
        T[f4*4+0][c] = v.x; T[f4*4+1][c] = v.y;
        T[f4*4+2][c] = v.z; T[f4*4+3][c] = v.w;
    }
    __syncthreads();
    const int tl = tid >> 2, q = tid & 3;
    const size_t m = (size_t)b * TT + tt * 64 + tl;
    _Float16* outh = Zh + m * 512 + ct * 64 + q * 16;
#pragma unroll
    for (int g = 0; g < 2; ++g) {
        half8 hv;
#pragma unroll
        for (int jj = 0; jj < 8; ++jj)
            hv[jj] = (_Float16)(4.0f * T[tl][q*16 + g*8 + jj]);
        *(half8*)(outh + g * 8) = hv;
    }
}

// ---------------------------------------------------------------------------
// K0b: fp32 [rows][512] -> f16 hi/lo [rows][1024] at 64x scale.
// ---------------------------------------------------------------------------
__global__ __launch_bounds__(256) void k_prep_hl(
    const float* __restrict__ src, _Float16* __restrict__ dst)
{
    const int g = blockIdx.x * 256 + threadIdx.x;
    const int row = g >> 7, c4 = (g & 127) * 4;
    const float4 v = *(const float4*)(src + (size_t)row * 512 + c4);
    half4 h, l;
    const float s[4] = {v.x * 64.0f, v.y * 64.0f, v.z * 64.0f, v.w * 64.0f};
#pragma unroll
    for (int j = 0; j < 4; ++j) {
        const _Float16 hh = (_Float16)s[j];
        h[j] = hh;
        l[j] = (_Float16)(s[j] - (float)hh);
    }
    *(half4*)(dst + (size_t)row * 1024 + c4) = h;
    *(half4*)(dst + (size_t)row * 1024 + 512 + c4) = l;
}

// ---------------------------------------------------------------------------
// K1: codebook GEMM via 3-term hi/lo f16 MFMA (fp32-grade ~1e-6):
// cb[n][d] = (eh.ph + eh.pl + el.ph)/4096 + pb[d]; Ch = f16(64*cb); cnorm.
// ---------------------------------------------------------------------------
__global__ __launch_bounds__(256) void k_cb(
    const _Float16* __restrict__ Eb, const _Float16* __restrict__ Wb,
    const float* __restrict__ pb, float* __restrict__ cb,
    _Float16* __restrict__ Ch, float* __restrict__ cnorm)
{
    __shared__ __align__(16) _Float16 As[128 * 64];
    __shared__ __align__(16) _Float16 Bs[128 * 64];

    const int tid = threadIdx.x;
    const int wave = tid >> 6, lane = tid & 63;
    const int n0 = blockIdx.x * 128, d0 = blockIdx.y * 128;
    const int wm = wave >> 1, wn = wave & 1;
    const int lm = lane & 15, lq = lane >> 4;

    floatx4 acc[4][4];
#pragma unroll
    for (int i = 0; i < 4; ++i)
#pragma unroll
        for (int j = 0; j < 4; ++j) acc[i][j] = (floatx4)0.0f;

    for (int lc = 0; lc < 24; ++lc) {
        const int kA = (lc < 8) ? lc * 64 : (lc < 16 ? (lc - 8) * 64 : 512 + (lc - 16) * 64);
        const int kB = (lc < 8) ? lc * 64 : (lc < 16 ? 512 + (lc - 8) * 64 : (lc - 16) * 64);

        __syncthreads();
#pragma unroll
        for (int r = 0; r < 4; ++r) {
            const int s = wave * 4 + r;
            const int row = s * 8 + (lane >> 3);
            const int src = (lane & 7) ^ (row & 7);
            async_copy16(&As[s * 512], Eb + (size_t)(n0 + row) * 1024 + kA + src * 8);
            async_copy16(&Bs[s * 512], Wb + (size_t)(d0 + row) * 1024 + kB + src * 8);
        }
        __syncthreads();

#pragma unroll
        for (int ks = 0; ks < 2; ++ks) {
            half8 af[4], bf[4];
#pragma unroll
            for (int i = 0; i < 4; ++i) {
                const int row = wm * 64 + i * 16 + lm;
                const int slot = (ks * 4 + lq) ^ (row & 7);
                af[i] = *(const half8*)&As[row * 64 + slot * 8];
            }
#pragma unroll
            for (int j = 0; j < 4; ++j) {
                const int row = wn * 64 + j * 16 + lm;
                const int slot = (ks * 4 + lq) ^ (row & 7);
                bf[j] = *(const half8*)&Bs[row * 64 + slot * 8];
            }
#pragma unroll
            for (int i = 0; i < 4; ++i)
#pragma unroll
                for (int j = 0; j < 4; ++j)
                    acc[i][j] = __builtin_amdgcn_mfma_f32_16x16x32_f16(af[i], bf[j], acc[i][j], 0, 0, 0);
        }
    }

    float bias[4];
#pragma unroll
    for (int j = 0; j < 4; ++j) bias[j] = pb[d0 + wn * 64 + j * 16 + lm];

    float nsum[16];
#pragma unroll
    for (int p = 0; p < 16; ++p) nsum[p] = 0.0f;

#pragma unroll
    for (int i = 0; i < 4; ++i) {
#pragma unroll
        for (int j = 0; j < 4; ++j) {
            const int d = d0 + wn * 64 + j * 16 + lm;
#pragma unroll
            for (int r = 0; r < 4; ++r) {
                const float v = acc[i][j][r] * 0.000244140625f + bias[j];  // 1/4096
                const int n = n0 + wm * 64 + i * 16 + lq * 4 + r;
                cb[(size_t)n * 512 + d] = v;
                Ch[(size_t)n * 512 + d] = (_Float16)(v * 64.0f);
                nsum[i * 4 + r] += v * v;
            }
        }
    }
#pragma unroll
    for (int stp = 1; stp < 16; stp <<= 1) {
#pragma unroll
        for (int p = 0; p < 16; ++p) nsum[p] += __shfl_xor(nsum[p], stp);
    }
    float myv = nsum[0];
#pragma unroll
    for (int p = 1; p < 16; ++p) if (lm == p) myv = nsum[p];
    const int n = n0 + wm * 64 + (lm >> 2) * 16 + lq * 4 + (lm & 3);
    atomicAdd(&cnorm[n], myv);
}

// ---------------------------------------------------------------------------
// K2: coarse distance GEMM (hi-only, K=512). f = cnorm[n] - zh.ch/128.
// Emits per-(row, 8-code unit) minima into bmin[m][1024] (f16), staged
// through LDS for coalesced global stores.
// ---------------------------------------------------------------------------
__global__ __launch_bounds__(256) void k_coarse(
    const _Float16* __restrict__ Zh, const _Float16* __restrict__ Ch,
    const float* __restrict__ cnorm, const int* __restrict__ dom_arr,
    _Float16* __restrict__ bmin)
{
    const int mt = blockIdx.x;          // 0..63
    const int nt = blockIdx.y;          // 0..63
    const int b = mt >> 3;
    const int dom = dom_arr[b];
    const int chunk = nt >> 4;
    const bool valid = (dom == 3) || (dom == 0 && chunk == 0) ||
                       (dom == 1 && chunk == 1) || (dom == 2 && chunk >= 2);
    if (!valid) return;

    __shared__ __align__(16) _Float16 As[128 * 64];
    __shared__ __align__(16) _Float16 Bs[128 * 64];
    __shared__ __align__(16) _Float16 bmin_s[128][16];

    const int tid = threadIdx.x;
    const int wave = tid >> 6, lane = tid & 63;
    const int m0 = mt * 128, n0 = nt * 128;
    const int wm = wave >> 1, wn = wave & 1;
    const int lm = lane & 15, lq = lane >> 4;

    floatx4 acc[4][4];
#pragma unroll
    for (int i = 0; i < 4; ++i)
#pragma unroll
        for (int j = 0; j < 4; ++j) acc[i][j] = (floatx4)0.0f;

    for (int lc = 0; lc < 8; ++lc) {
        const int kk0 = lc * 64;
        __syncthreads();
#pragma unroll
        for (int r = 0; r < 4; ++r) {
            const int s = wave * 4 + r;
            const int row = s * 8 + (lane >> 3);
            const int src = (lane & 7) ^ (row & 7);
            async_copy16(&As[s * 512], Zh + (size_t)(m0 + row) * 512 + kk0 + src * 8);
            async_copy16(&Bs[s * 512], Ch + (size_t)(n0 + row) * 512 + kk0 + src * 8);
        }
        __syncthreads();

#pragma unroll
        for (int ks = 0; ks < 2; ++ks) {
            half8 af[4], bf[4];
#pragma unroll
            for (int i = 0; i < 4; ++i) {
                const int row = wm * 64 + i * 16 + lm;
                const int slot = (ks * 4 + lq) ^ (row & 7);
                af[i] = *(const half8*)&As[row * 64 + slot * 8];
            }
#pragma unroll
            for (int j = 0; j < 4; ++j) {
                const int row = wn * 64 + j * 16 + lm;
                const int slot = (ks * 4 + lq) ^ (row & 7);
                bf[j] = *(const half8*)&Bs[row * 64 + slot * 8];
            }
#pragma unroll
            for (int i = 0; i < 4; ++i)
#pragma unroll
                for (int j = 0; j < 4; ++j)
                    acc[i][j] = __builtin_amdgcn_mfma_f32_16x16x32_f16(af[i], bf[j], acc[i][j], 0, 0, 0);
        }
    }

    // scores in place: f = cnorm - acc/128
#pragma unroll
    for (int j = 0; j < 4; ++j) {
        const float cn = cnorm[n0 + wn * 64 + j * 16 + lm];
#pragma unroll
        for (int i = 0; i < 4; ++i)
#pragma unroll
            for (int r = 0; r < 4; ++r)
                acc[i][j][r] = cn - acc[i][j][r] * 0.0078125f;
    }
    // 8-code unit minima: reduce across lm&7
#pragma unroll
    for (int stp = 1; stp < 8; stp <<= 1) {
#pragma unroll
        for (int i = 0; i < 4; ++i)
#pragma unroll
            for (int j = 0; j < 4; ++j)
#pragma unroll
                for (int r = 0; r < 4; ++r)
                    acc[i][j][r] = fminf(acc[i][j][r], __shfl_xor(acc[i][j][r], stp));
    }
    if ((lm & 7) == 0) {
        const int b3 = lm >> 3;
#pragma unroll
        for (int i = 0; i < 4; ++i)
#pragma unroll
            for (int j = 0; j < 4; ++j)
#pragma unroll
                for (int r = 0; r < 4; ++r)
                    bmin_s[wm * 64 + i * 16 + lq * 4 + r][wn * 8 + j * 2 + b3] =
                        (_Float16)acc[i][j][r];
    }
    __syncthreads();
    {   // coalesced-ish writeout: 16B per thread
        const int r = tid >> 1, h = tid & 1;
        const half8 v = *(const half8*)&bmin_s[r][h * 8];
        *(half8*)(bmin + (size_t)(m0 + r) * 1024 + nt * 16 + h * 8) = v;
    }
}

// ---------------------------------------------------------------------------
// K3: refine. One wave per z-row: gmin over 1024 unit-minima; exact fp32
// rescoring of codes in units within MARGIN. Ascending scan -> first min,
// matching jnp.argmin tie semantics.
// ---------------------------------------------------------------------------
__global__ __launch_bounds__(256) void k_refine(
    const float* __restrict__ z, const float* __restrict__ cb,
    const float* __restrict__ cnorm, const _Float16* __restrict__ bmin,
    int* __restrict__ minidx, float* __restrict__ out_idx)
{
    const int m = blockIdx.x * 4 + (threadIdx.x >> 6);
    const int lane = threadIdx.x & 63;
    const int b = m >> 10, t = m & 1023;

    // 16 unit minima per lane (units lane*16 .. lane*16+15); NaN = invalid
    const _Float16* brow = bmin + (size_t)m * 1024 + lane * 16;
    const half8 u0 = *(const half8*)brow;
    const half8 u1 = *(const half8*)(brow + 8);
    float um[16];
#pragma unroll
    for (int k = 0; k < 8; ++k) { um[k] = (float)u0[k]; um[8 + k] = (float)u1[k]; }

    float g = FLT_BIG;
#pragma unroll
    for (int k = 0; k < 16; ++k) g = fminf(g, um[k]);   // fminf drops NaN
#pragma unroll
    for (int s = 32; s > 0; s >>= 1) g = fminf(g, __shfl_xor(g, s));
    const float thr = g + MARGIN;

    float zr[8];
#pragma unroll
    for (int j = 0; j < 8; ++j)
        zr[j] = z[((size_t)(b * ED + lane + 64 * j)) * TT + t];

    float bestv = FLT_BIG; int besti = 0;

    bool any = false;
#pragma unroll
    for (int k = 0; k < 16; ++k) any |= (um[k] <= thr);
    unsigned long long mask = __ballot(any);

    while (mask) {
        const int L = __ffsll(mask) - 1;
        mask &= mask - 1;
#pragma unroll
        for (int k = 0; k < 16; ++k) {
            const float uv = __shfl(um[k], L);
            if (!(uv <= thr)) continue;          // NaN-safe skip
            const int nbase = (L * 16 + k) * 8;
            for (int q = 0; q < 8; q += 2) {
                const float* r0 = cb + (size_t)(nbase + q) * 512 + lane;
                const float* r1 = r0 + 512;
                float d0 = 0.f, d1 = 0.f;
#pragma unroll
                for (int j = 0; j < 8; ++j) {
                    d0 += zr[j] * r0[64 * j];
                    d1 += zr[j] * r1[64 * j];
                }
#pragma unroll
                for (int s = 32; s > 0; s >>= 1) {
                    d0 += __shfl_xor(d0, s);
                    d1 += __shfl_xor(d1, s);
                }
                const float f0 = cnorm[nbase + q]     - 2.0f * d0;
                const float f1 = cnorm[nbase + q + 1] - 2.0f * d1;
                if (f0 < bestv) { bestv = f0; besti = nbase + q; }
                if (f1 < bestv) { bestv = f1; besti = nbase + q + 1; }
            }
        }
    }
    if (lane == 0) {
        minidx[m] = besti;
        out_idx[m] = (float)besti;
    }
}

// ---------------------------------------------------------------------------
// K4: z_q gather (fp32 codebook) + transpose to (B,C,T) + commit loss.
// ---------------------------------------------------------------------------
__global__ __launch_bounds__(256) void k_zq(
    const float* __restrict__ z, const float* __restrict__ cb,
    const int* __restrict__ minidx, float* __restrict__ outz,
    float* __restrict__ lossacc)
{
    __shared__ float red[4];
    const int blk = blockIdx.x;
    const int b = blk >> 4;
    const int t0 = (blk & 15) * 64;
    const int tl = threadIdx.x & 63;
    const int cg = threadIdx.x >> 6;
    const int t = t0 + tl;
    const int idx = minidx[b * TT + t];
    const float* __restrict__ crow = cb + (size_t)idx * 512;

    float lsum = 0.f;
    for (int c = cg; c < ED; c += 4) {
        const float cv = crow[c];
        const size_t off = ((size_t)(b * ED + c)) * TT + t;
        const float zv = z[off];
        const float d = cv - zv;
        lsum += d * d;
        outz[off] = cv;
    }
#pragma unroll
    for (int off = 32; off > 0; off >>= 1) lsum += __shfl_down(lsum, off);
    if (tl == 0) red[threadIdx.x >> 6] = lsum;
    __syncthreads();
    if (threadIdx.x == 0)
        atomicAdd(lossacc, red[0] + red[1] + red[2] + red[3]);
}

__global__ void k_final(const float* __restrict__ lossacc, float* __restrict__ outloss)
{
    *outloss = 1.25f * (*lossacc) / (float)(BB * ED * TT);
}

// ---------------------------------------------------------------------------
extern "C" void kernel_launch(void* const* d_in, const int* in_sizes, int n_in,
                              void* d_out, int out_size, void* d_ws, size_t ws_size,
                              hipStream_t stream)
{
    const float* z   = (const float*)d_in[0];
    const int*   dom = (const int*)d_in[1];
    const float* emb = (const float*)d_in[3];
    const float* pw  = (const float*)d_in[4];
    const float* pb  = (const float*)d_in[5];
    float* out = (float*)d_out;

    char* p = (char*)d_ws;
    _Float16* Zh = (_Float16*)p;            p += (size_t)MM * 512 * 2;   // 8 MB
    _Float16* Eb = (_Float16*)p;            p += (size_t)NE * 1024 * 2;  // 16 MB
    _Float16* Wb = (_Float16*)p;            p += (size_t)ED * 1024 * 2;  // 1 MB
    float*    cb = (float*)p;               p += (size_t)NE * 512 * 4;   // 16 MB
    _Float16* Ch = (_Float16*)p;            p += (size_t)NE * 512 * 2;   // 8 MB
    float* cnorm = (float*)p;               p += (size_t)NE * 4;
    _Float16* bmin = (_Float16*)p;          p += (size_t)MM * 1024 * 2;  // 16 MB
    int*   minidx = (int*)p;                p += (size_t)MM * 4;
    float* lossacc = (float*)p;

    hipMemsetAsync(cnorm, 0, NE * sizeof(float), stream);
    hipMemsetAsync(bmin, 0x7F, (size_t)MM * 1024 * 2, stream);  // f16 NaN
    hipMemsetAsync(lossacc, 0, sizeof(float), stream);

    k_prep_z <<<dim3(8, 16, 8), 256, 0, stream>>>(z, Zh);
    k_prep_hl<<<NE / 2, 256, 0, stream>>>(emb, Eb);
    k_prep_hl<<<ED / 2, 256, 0, stream>>>(pw, Wb);
    k_cb     <<<dim3(64, 4), 256, 0, stream>>>(Eb, Wb, pb, cb, Ch, cnorm);
    k_coarse <<<dim3(64, 64), 256, 0, stream>>>(Zh, Ch, cnorm, dom, bmin);
    k_refine <<<MM / 4, 256, 0, stream>>>(z, cb, cnorm, bmin, minidx, out + (size_t)NE * ED);
    k_zq     <<<128, 256, 0, stream>>>(z, cb, minidx, out, lossacc);
    k_final  <<<1, 1, 0, stream>>>(lossacc, out + (size_t)NE * ED + MM);
}

// Round 5
// 269.691 us; speedup vs baseline: 3.4915x; 1.2636x over previous
//
#include <hip/hip_runtime.h>
#include <math.h>

#define NE   8192
#define ED   512
#define BB   8
#define TT   1024
#define MM   (BB*TT)

#define FLT_BIG 3.402823466e38f
#define MARGIN  0.08f

typedef _Float16 half8 __attribute__((ext_vector_type(8)));
typedef _Float16 half4 __attribute__((ext_vector_type(4)));
typedef float    floatx4 __attribute__((ext_vector_type(4)));

typedef __attribute__((address_space(3))) unsigned int       lds_u32;
typedef const __attribute__((address_space(1))) unsigned int gbl_u32;

__device__ __forceinline__ void async_copy16(void* lds, const void* g) {
    __builtin_amdgcn_global_load_lds((gbl_u32*)(unsigned long long)g,
                                     (lds_u32*)(unsigned long long)lds,
                                     16, 0, 0);
}

// ---------------------------------------------------------------------------
// K0: z (B,C,T) fp32 -> Zh[m][512] = f16(4z), m = b*T + t. 64x64 transpose.
// ---------------------------------------------------------------------------
__global__ __launch_bounds__(256) void k_prep_z(
    const float* __restrict__ z, _Float16* __restrict__ Zh)
{
    __shared__ float T[64][65];
    const int ct = blockIdx.x, tt = blockIdx.y, b = blockIdx.z;
    const int tid = threadIdx.x;
    const int f4 = tid & 15;
    const int c0 = tid >> 4;
#pragma unroll
    for (int r = 0; r < 4; ++r) {
        const int c = c0 + r * 16;
        const float4 v = *(const float4*)(z + ((size_t)(b * ED + ct * 64 + c)) * TT + tt * 64 + f4 * 4);
        T[f4*4+0][c] = v.x; T[f4*4+1][c] = v.y;
        T[f4*4+2][c] = v.z; T[f4*4+3][c] = v.w;
    }
    __syncthreads();
    const int tl = tid >> 2, q = tid & 3;
    const size_t m = (size_t)b * TT + tt * 64 + tl;
    _Float16* outh = Zh + m * 512 + ct * 64 + q * 16;
#pragma unroll
    for (int g = 0; g < 2; ++g) {
        half8 hv;
#pragma unroll
        for (int jj = 0; jj < 8; ++jj)
            hv[jj] = (_Float16)(4.0f * T[tl][q*16 + g*8 + jj]);
        *(half8*)(outh + g * 8) = hv;
    }
}

// ---------------------------------------------------------------------------
// K0b (fused): fp32 [rows][512] -> f16 hi/lo [rows][1024] at 64x scale,
// for emb (rows<NE) and pw (rows>=NE) in one launch.
// ---------------------------------------------------------------------------
__global__ __launch_bounds__(256) void k_prep_hl(
    const float* __restrict__ emb, const float* __restrict__ pw,
    _Float16* __restrict__ Eb, _Float16* __restrict__ Wb)
{
    const int g = blockIdx.x * 256 + threadIdx.x;
    const int row = g >> 7, c4 = (g & 127) * 4;
    const float* src;
    _Float16* dst;
    if (row < NE) { src = emb + (size_t)row * 512;        dst = Eb + (size_t)row * 1024; }
    else          { src = pw + (size_t)(row - NE) * 512;  dst = Wb + (size_t)(row - NE) * 1024; }
    const float4 v = *(const float4*)(src + c4);
    half4 h, l;
    const float s[4] = {v.x * 64.0f, v.y * 64.0f, v.z * 64.0f, v.w * 64.0f};
#pragma unroll
    for (int j = 0; j < 4; ++j) {
        const _Float16 hh = (_Float16)s[j];
        h[j] = hh;
        l[j] = (_Float16)(s[j] - (float)hh);
    }
    *(half4*)(dst + c4) = h;
    *(half4*)(dst + 512 + c4) = l;
}

// ---------------------------------------------------------------------------
// K1: codebook GEMM via 3-term hi/lo f16 MFMA (fp32-grade ~1e-6).
// 64x64 tiles, grid (128,8)=1024 blocks for occupancy (skinny-N fix).
// cb[n][d] = (eh.ph + eh.pl + el.ph)/4096 + pb[d]; Ch = f16(64*cb); cnorm.
// ---------------------------------------------------------------------------
__global__ __launch_bounds__(256) void k_cb(
    const _Float16* __restrict__ Eb, const _Float16* __restrict__ Wb,
    const float* __restrict__ pb, float* __restrict__ cb,
    _Float16* __restrict__ Ch, float* __restrict__ cnorm)
{
    __shared__ __align__(16) _Float16 As[64 * 64];
    __shared__ __align__(16) _Float16 Bs[64 * 64];

    const int tid = threadIdx.x;
    const int wave = tid >> 6, lane = tid & 63;
    const int n0 = blockIdx.x * 64, d0 = blockIdx.y * 64;
    const int wm = wave >> 1, wn = wave & 1;      // wave tile 32x32
    const int lm = lane & 15, lq = lane >> 4;

    floatx4 acc[2][2];
#pragma unroll
    for (int i = 0; i < 2; ++i)
#pragma unroll
        for (int j = 0; j < 2; ++j) acc[i][j] = (floatx4)0.0f;

    for (int lc = 0; lc < 24; ++lc) {
        const int kA = (lc < 8) ? lc * 64 : (lc < 16 ? (lc - 8) * 64 : 512 + (lc - 16) * 64);
        const int kB = (lc < 8) ? lc * 64 : (lc < 16 ? 512 + (lc - 8) * 64 : (lc - 16) * 64);

        __syncthreads();
#pragma unroll
        for (int r2 = 0; r2 < 2; ++r2) {
            const int s = wave + r2 * 4;          // 8 spans of 1KB (8 rows)
            const int row = s * 8 + (lane >> 3);
            const int src = (lane & 7) ^ (row & 7);
            async_copy16(&As[s * 512], Eb + (size_t)(n0 + row) * 1024 + kA + src * 8);
            async_copy16(&Bs[s * 512], Wb + (size_t)(d0 + row) * 1024 + kB + src * 8);
        }
        __syncthreads();

#pragma unroll
        for (int ks = 0; ks < 2; ++ks) {
            half8 af[2], bf[2];
#pragma unroll
            for (int i = 0; i < 2; ++i) {
                const int row = wm * 32 + i * 16 + lm;
                const int slot = (ks * 4 + lq) ^ (row & 7);
                af[i] = *(const half8*)&As[row * 64 + slot * 8];
            }
#pragma unroll
            for (int j = 0; j < 2; ++j) {
                const int row = wn * 32 + j * 16 + lm;
                const int slot = (ks * 4 + lq) ^ (row & 7);
                bf[j] = *(const half8*)&Bs[row * 64 + slot * 8];
            }
#pragma unroll
            for (int i = 0; i < 2; ++i)
#pragma unroll
                for (int j = 0; j < 2; ++j)
                    acc[i][j] = __builtin_amdgcn_mfma_f32_16x16x32_f16(af[i], bf[j], acc[i][j], 0, 0, 0);
        }
    }

    float bias[2];
#pragma unroll
    for (int j = 0; j < 2; ++j) bias[j] = pb[d0 + wn * 32 + j * 16 + lm];

    float nsum[8];
#pragma unroll
    for (int p = 0; p < 8; ++p) nsum[p] = 0.0f;

#pragma unroll
    for (int i = 0; i < 2; ++i) {
#pragma unroll
        for (int j = 0; j < 2; ++j) {
            const int d = d0 + wn * 32 + j * 16 + lm;
#pragma unroll
            for (int r = 0; r < 4; ++r) {
                const float v = acc[i][j][r] * 0.000244140625f + bias[j];  // 1/4096
                const int n = n0 + wm * 32 + i * 16 + lq * 4 + r;
                cb[(size_t)n * 512 + d] = v;
                Ch[(size_t)n * 512 + d] = (_Float16)(v * 64.0f);
                nsum[i * 4 + r] += v * v;
            }
        }
    }
#pragma unroll
    for (int stp = 1; stp < 16; stp <<= 1) {
#pragma unroll
        for (int p = 0; p < 8; ++p) nsum[p] += __shfl_xor(nsum[p], stp);
    }
    float myv = nsum[0];
#pragma unroll
    for (int p = 1; p < 8; ++p) if (lm == p) myv = nsum[p];
    if (lm < 8) {
        const int n = n0 + wm * 32 + (lm >> 2) * 16 + lq * 4 + (lm & 3);
        atomicAdd(&cnorm[n], myv);
    }
}

// ---------------------------------------------------------------------------
// K2: coarse distance GEMM (hi-only, K=512), CODES ON MFMA ROWS (A=Ch),
// z on cols (B=Zh). f = cnorm[n] - ch.zh/128. The 8-code unit min is then
// mostly in-lane: 48 fminf + 16 shfl instead of 192 shfl + 192 fminf.
// Emits per-(row m, 8-code unit) minima into bmin[m][1024] (f16).
// ---------------------------------------------------------------------------
__global__ __launch_bounds__(256) void k_coarse(
    const _Float16* __restrict__ Zh, const _Float16* __restrict__ Ch,
    const float* __restrict__ cnorm, const int* __restrict__ dom_arr,
    _Float16* __restrict__ bmin)
{
    const int mt = blockIdx.x;          // z-tile 0..63
    const int nt = blockIdx.y;          // code-tile 0..63
    const int b = mt >> 3;
    const int dom = dom_arr[b];
    const int chunk = nt >> 4;
    const bool valid = (dom == 3) || (dom == 0 && chunk == 0) ||
                       (dom == 1 && chunk == 1) || (dom == 2 && chunk >= 2);
    if (!valid) return;

    __shared__ __align__(16) _Float16 As[128 * 64];      // codes
    __shared__ __align__(16) _Float16 Bs[128 * 64];      // z
    __shared__ __align__(16) _Float16 bs[128][20];       // [m_local][unit], padded

    const int tid = threadIdx.x;
    const int wave = tid >> 6, lane = tid & 63;
    const int m0 = mt * 128, n0 = nt * 128;
    const int wm = wave >> 1, wn = wave & 1;   // wm: code rows, wn: z cols
    const int lm = lane & 15, lq = lane >> 4;

    floatx4 acc[4][4];
#pragma unroll
    for (int i = 0; i < 4; ++i)
#pragma unroll
        for (int j = 0; j < 4; ++j) acc[i][j] = (floatx4)0.0f;

    for (int lc = 0; lc < 8; ++lc) {
        const int kk0 = lc * 64;
        __syncthreads();
#pragma unroll
        for (int r = 0; r < 4; ++r) {
            const int s = wave * 4 + r;
            const int row = s * 8 + (lane >> 3);
            const int src = (lane & 7) ^ (row & 7);
            async_copy16(&As[s * 512], Ch + (size_t)(n0 + row) * 512 + kk0 + src * 8);
            async_copy16(&Bs[s * 512], Zh + (size_t)(m0 + row) * 512 + kk0 + src * 8);
        }
        __syncthreads();

#pragma unroll
        for (int ks = 0; ks < 2; ++ks) {
            half8 af[4], bf[4];
#pragma unroll
            for (int i = 0; i < 4; ++i) {
                const int row = wm * 64 + i * 16 + lm;            // code row
                const int slot = (ks * 4 + lq) ^ (row & 7);
                af[i] = *(const half8*)&As[row * 64 + slot * 8];
            }
#pragma unroll
            for (int j = 0; j < 4; ++j) {
                const int row = wn * 64 + j * 16 + lm;            // z row
                const int slot = (ks * 4 + lq) ^ (row & 7);
                bf[j] = *(const half8*)&Bs[row * 64 + slot * 8];
            }
#pragma unroll
            for (int i = 0; i < 4; ++i)
#pragma unroll
                for (int j = 0; j < 4; ++j)
                    acc[i][j] = __builtin_amdgcn_mfma_f32_16x16x32_f16(af[i], bf[j], acc[i][j], 0, 0, 0);
        }
    }

    // D layout: row (code) = wm*64 + i*16 + lq*4 + r, col (z) = wn*64 + j*16 + lm
    float cnv[4][4];
#pragma unroll
    for (int i = 0; i < 4; ++i)
#pragma unroll
        for (int r = 0; r < 4; ++r)
            cnv[i][r] = cnorm[n0 + wm * 64 + i * 16 + lq * 4 + r];

    float um[4][4];   // [i][j] unit-min over this lane's 4 code rows
#pragma unroll
    for (int i = 0; i < 4; ++i) {
#pragma unroll
        for (int j = 0; j < 4; ++j) {
            float m01 = fminf(cnv[i][0] - acc[i][j][0] * 0.0078125f,
                              cnv[i][1] - acc[i][j][1] * 0.0078125f);
            float m23 = fminf(cnv[i][2] - acc[i][j][2] * 0.0078125f,
                              cnv[i][3] - acc[i][j][3] * 0.0078125f);
            um[i][j] = fminf(m01, m23);
        }
    }
    // combine lq pairs {0,1},{2,3} (rows p*8..p*8+7 form one 8-code unit)
#pragma unroll
    for (int i = 0; i < 4; ++i)
#pragma unroll
        for (int j = 0; j < 4; ++j)
            um[i][j] = fminf(um[i][j], __shfl_xor(um[i][j], 16));

    if ((lq & 1) == 0) {
        const int p = lq >> 1;
#pragma unroll
        for (int i = 0; i < 4; ++i)
#pragma unroll
            for (int j = 0; j < 4; ++j)
                bs[wn * 64 + j * 16 + lm][wm * 8 + i * 2 + p] = (_Float16)um[i][j];
    }
    __syncthreads();
    {   // writeout: [m][unit] -> bmin[m0+m][nt*16 + u]
        const int r = tid >> 1, h = tid & 1;
        half8 v;
#pragma unroll
        for (int k = 0; k < 8; ++k) v[k] = bs[r][h * 8 + k];
        *(half8*)(bmin + (size_t)(m0 + r) * 1024 + nt * 16 + h * 8) = v;
    }
}

// ---------------------------------------------------------------------------
// K3: refine. One wave per z-row: gmin over 1024 unit-minima; exact fp32
// rescoring of codes in units within MARGIN. Ascending scan -> first min.
// ---------------------------------------------------------------------------
__global__ __launch_bounds__(256) void k_refine(
    const float* __restrict__ z, const float* __restrict__ cb,
    const float* __restrict__ cnorm, const _Float16* __restrict__ bmin,
    int* __restrict__ minidx, float* __restrict__ out_idx)
{
    const int m = blockIdx.x * 4 + (threadIdx.x >> 6);
    const int lane = threadIdx.x & 63;
    const int b = m >> 10, t = m & 1023;

    const _Float16* brow = bmin + (size_t)m * 1024 + lane * 16;
    const half8 u0 = *(const half8*)brow;
    const half8 u1 = *(const half8*)(brow + 8);
    float um[16];
#pragma unroll
    for (int k = 0; k < 8; ++k) { um[k] = (float)u0[k]; um[8 + k] = (float)u1[k]; }

    float g = FLT_BIG;
#pragma unroll
    for (int k = 0; k < 16; ++k) g = fminf(g, um[k]);   // fminf drops NaN
#pragma unroll
    for (int s = 32; s > 0; s >>= 1) g = fminf(g, __shfl_xor(g, s));
    const float thr = g + MARGIN;

    float zr[8];
#pragma unroll
    for (int j = 0; j < 8; ++j)
        zr[j] = z[((size_t)(b * ED + lane + 64 * j)) * TT + t];

    float bestv = FLT_BIG; int besti = 0;

    bool any = false;
#pragma unroll
    for (int k = 0; k < 16; ++k) any |= (um[k] <= thr);
    unsigned long long mask = __ballot(any);

    while (mask) {
        const int L = __ffsll(mask) - 1;
        mask &= mask - 1;
#pragma unroll
        for (int k = 0; k < 16; ++k) {
            const float uv = __shfl(um[k], L);
            if (!(uv <= thr)) continue;          // NaN-safe skip
            const int nbase = (L * 16 + k) * 8;
            for (int q = 0; q < 8; q += 2) {
                const float* r0 = cb + (size_t)(nbase + q) * 512 + lane;
                const float* r1 = r0 + 512;
                float d0 = 0.f, d1 = 0.f;
#pragma unroll
                for (int j = 0; j < 8; ++j) {
                    d0 += zr[j] * r0[64 * j];
                    d1 += zr[j] * r1[64 * j];
                }
#pragma unroll
                for (int s = 32; s > 0; s >>= 1) {
                    d0 += __shfl_xor(d0, s);
                    d1 += __shfl_xor(d1, s);
                }
                const float f0 = cnorm[nbase + q]     - 2.0f * d0;
                const float f1 = cnorm[nbase + q + 1] - 2.0f * d1;
                if (f0 < bestv) { bestv = f0; besti = nbase + q; }
                if (f1 < bestv) { bestv = f1; besti = nbase + q + 1; }
            }
        }
    }
    if (lane == 0) {
        minidx[m] = besti;
        out_idx[m] = (float)besti;
    }
}

// ---------------------------------------------------------------------------
// K4: z_q gather + transpose to (B,C,T) + commit loss (finalized in-kernel
// by the last block via device-scope completion counter).
// grid (4,16,8) = 512 blocks: cc = 128-c window, tt = 64-t tile, b.
// ---------------------------------------------------------------------------
#define ZQ_BLOCKS (4*16*8)
__global__ __launch_bounds__(256) void k_zq(
    const float* __restrict__ z, const float* __restrict__ cb,
    const int* __restrict__ minidx, float* __restrict__ outz,
    float* __restrict__ lossacc, unsigned int* __restrict__ donecnt,
    float* __restrict__ outloss)
{
    __shared__ float red[4];
    const int cc = blockIdx.x, tt = blockIdx.y, b = blockIdx.z;
    const int tl = threadIdx.x & 63;
    const int cg = threadIdx.x >> 6;
    const int t = tt * 64 + tl;
    const int idx = minidx[b * TT + t];
    const float* __restrict__ crow = cb + (size_t)idx * 512;

    float lsum = 0.f;
#pragma unroll 8
    for (int k = 0; k < 32; ++k) {
        const int c = cc * 128 + cg + k * 4;
        const float cv = crow[c];
        const size_t off = ((size_t)(b * ED + c)) * TT + t;
        const float zv = z[off];
        const float d = cv - zv;
        lsum += d * d;
        outz[off] = cv;
    }
#pragma unroll
    for (int off = 32; off > 0; off >>= 1) lsum += __shfl_down(lsum, off);
    if (tl == 0) red[threadIdx.x >> 6] = lsum;
    __syncthreads();
    if (threadIdx.x == 0) {
        atomicAdd(lossacc, red[0] + red[1] + red[2] + red[3]);
        __threadfence();
        const unsigned int old = atomicAdd(donecnt, 1u);
        if (old == ZQ_BLOCKS - 1) {
            const float total = atomicAdd(lossacc, 0.0f);  // forces L2 read
            *outloss = 1.25f * total / (float)(BB * ED * TT);
        }
    }
}

// ---------------------------------------------------------------------------
extern "C" void kernel_launch(void* const* d_in, const int* in_sizes, int n_in,
                              void* d_out, int out_size, void* d_ws, size_t ws_size,
                              hipStream_t stream)
{
    const float* z   = (const float*)d_in[0];
    const int*   dom = (const int*)d_in[1];
    const float* emb = (const float*)d_in[3];
    const float* pw  = (const float*)d_in[4];
    const float* pb  = (const float*)d_in[5];
    float* out = (float*)d_out;

    char* p = (char*)d_ws;
    _Float16* Zh = (_Float16*)p;            p += (size_t)MM * 512 * 2;   // 8 MB
    _Float16* Eb = (_Float16*)p;            p += (size_t)NE * 1024 * 2;  // 16 MB
    _Float16* Wb = (_Float16*)p;            p += (size_t)ED * 1024 * 2;  // 1 MB
    float*    cb = (float*)p;               p += (size_t)NE * 512 * 4;   // 16 MB
    _Float16* Ch = (_Float16*)p;            p += (size_t)NE * 512 * 2;   // 8 MB
    float* cnorm = (float*)p;               p += (size_t)NE * 4;
    _Float16* bmin = (_Float16*)p;          p += (size_t)MM * 1024 * 2;  // 16 MB
    int*   minidx = (int*)p;                p += (size_t)MM * 4;
    float* lossacc = (float*)p;             p += 4;
    unsigned int* donecnt = (unsigned int*)p;

    hipMemsetAsync(cnorm, 0, NE * sizeof(float), stream);
    hipMemsetAsync(bmin, 0x7F, (size_t)MM * 1024 * 2, stream);  // f16 NaN
    hipMemsetAsync(lossacc, 0, 8, stream);                      // loss + counter

    k_prep_z <<<dim3(8, 16, 8), 256, 0, stream>>>(z, Zh);
    k_prep_hl<<<(NE + ED) / 2, 256, 0, stream>>>(emb, pw, Eb, Wb);
    k_cb     <<<dim3(128, 8), 256, 0, stream>>>(Eb, Wb, pb, cb, Ch, cnorm);
    k_coarse <<<dim3(64, 64), 256, 0, stream>>>(Zh, Ch, cnorm, dom, bmin);
    k_refine <<<MM / 4, 256, 0, stream>>>(z, cb, cnorm, bmin, minidx, out + (size_t)NE * ED);
    k_zq     <<<dim3(4, 16, 8), 256, 0, stream>>>(z, cb, minidx, out, lossacc, donecnt,
                                                  out + (size_t)NE * ED + MM);
}

// Round 6
// 257.557 us; speedup vs baseline: 3.6560x; 1.0471x over previous
//
#include <hip/hip_runtime.h>
#include <math.h>

#define NE   8192
#define ED   512
#define BB   8
#define TT   1024
#define MM   (BB*TT)

#define FLT_BIG 3.402823466e38f
#define MARGIN  0.08f

typedef _Float16 half8 __attribute__((ext_vector_type(8)));
typedef _Float16 half4 __attribute__((ext_vector_type(4)));
typedef float    floatx4 __attribute__((ext_vector_type(4)));

typedef __attribute__((address_space(3))) unsigned int       lds_u32;
typedef const __attribute__((address_space(1))) unsigned int gbl_u32;

__device__ __forceinline__ void async_copy16(void* lds, const void* g) {
    __builtin_amdgcn_global_load_lds((gbl_u32*)(unsigned long long)g,
                                     (lds_u32*)(unsigned long long)lds,
                                     16, 0, 0);
}

// ---------------------------------------------------------------------------
// K0: z (B,C,T) fp32 -> Zh[m][512] = f16(4z)  AND  Zt[m][512] = fp32 z row
// (coalesced source for k_refine). m = b*T + t. 64x64 transpose tiles.
// ---------------------------------------------------------------------------
__global__ __launch_bounds__(256) void k_prep_z(
    const float* __restrict__ z, _Float16* __restrict__ Zh,
    float* __restrict__ Zt)
{
    __shared__ float T[64][68];   // [t_local][c_local], stride 68 (16B-aligned)
    const int ct = blockIdx.x, tt = blockIdx.y, b = blockIdx.z;
    const int tid = threadIdx.x;
    const int f4 = tid & 15;
    const int c0 = tid >> 4;
#pragma unroll
    for (int r = 0; r < 4; ++r) {
        const int c = c0 + r * 16;
        const float4 v = *(const float4*)(z + ((size_t)(b * ED + ct * 64 + c)) * TT + tt * 64 + f4 * 4);
        T[f4*4+0][c] = v.x; T[f4*4+1][c] = v.y;
        T[f4*4+2][c] = v.z; T[f4*4+3][c] = v.w;
    }
    __syncthreads();
    {   // f16 hi write
        const int tl = tid >> 2, q = tid & 3;
        const size_t m = (size_t)b * TT + tt * 64 + tl;
        _Float16* outh = Zh + m * 512 + ct * 64 + q * 16;
#pragma unroll
        for (int g = 0; g < 2; ++g) {
            half8 hv;
#pragma unroll
            for (int jj = 0; jj < 8; ++jj)
                hv[jj] = (_Float16)(4.0f * T[tl][q*16 + g*8 + jj]);
            *(half8*)(outh + g * 8) = hv;
        }
    }
    {   // fp32 transposed write (coalesced float4)
        const int tl2 = tid >> 4;          // 0..15
        const int c4 = (tid & 15) * 4;
#pragma unroll
        for (int it = 0; it < 4; ++it) {
            const int t_local = tl2 + it * 16;
            const float4 v = *(const float4*)&T[t_local][c4];
            *(float4*)(Zt + ((size_t)b * TT + tt * 64 + t_local) * 512 + ct * 64 + c4) = v;
        }
    }
}

// ---------------------------------------------------------------------------
// K0b (fused): fp32 [rows][512] -> f16 hi/lo [rows][1024] at 64x scale,
// for emb (rows<NE) and pw (rows>=NE) in one launch.
// ---------------------------------------------------------------------------
__global__ __launch_bounds__(256) void k_prep_hl(
    const float* __restrict__ emb, const float* __restrict__ pw,
    _Float16* __restrict__ Eb, _Float16* __restrict__ Wb)
{
    const int g = blockIdx.x * 256 + threadIdx.x;
    const int row = g >> 7, c4 = (g & 127) * 4;
    const float* src;
    _Float16* dst;
    if (row < NE) { src = emb + (size_t)row * 512;        dst = Eb + (size_t)row * 1024; }
    else          { src = pw + (size_t)(row - NE) * 512;  dst = Wb + (size_t)(row - NE) * 1024; }
    const float4 v = *(const float4*)(src + c4);
    half4 h, l;
    const float s[4] = {v.x * 64.0f, v.y * 64.0f, v.z * 64.0f, v.w * 64.0f};
#pragma unroll
    for (int j = 0; j < 4; ++j) {
        const _Float16 hh = (_Float16)s[j];
        h[j] = hh;
        l[j] = (_Float16)(s[j] - (float)hh);
    }
    *(half4*)(dst + c4) = h;
    *(half4*)(dst + 512 + c4) = l;
}

// ---------------------------------------------------------------------------
// K1: codebook GEMM via 3-term hi/lo f16 MFMA (fp32-grade ~1e-6).
// Tile 128 codes x 64 d, grid (64,8)=512 blocks (2/CU). Wave tile 64x32:
// 8 MFMA per 6 ds_read_b128. cb, Ch=f16(64*cb), cnorm (atomic partials).
// ---------------------------------------------------------------------------
__global__ __launch_bounds__(256) void k_cb(
    const _Float16* __restrict__ Eb, const _Float16* __restrict__ Wb,
    const float* __restrict__ pb, float* __restrict__ cb,
    _Float16* __restrict__ Ch, float* __restrict__ cnorm)
{
    __shared__ __align__(16) _Float16 As[128 * 64];   // codes
    __shared__ __align__(16) _Float16 Bs[64 * 64];    // d

    const int tid = threadIdx.x;
    const int wave = tid >> 6, lane = tid & 63;
    const int n0 = blockIdx.x * 128, d0 = blockIdx.y * 64;
    const int wm = wave >> 1, wn = wave & 1;          // 2x2 waves -> 64x32 each
    const int lm = lane & 15, lq = lane >> 4;

    floatx4 acc[4][2];
#pragma unroll
    for (int i = 0; i < 4; ++i)
#pragma unroll
        for (int j = 0; j < 2; ++j) acc[i][j] = (floatx4)0.0f;

    for (int lc = 0; lc < 24; ++lc) {
        const int kA = (lc < 8) ? lc * 64 : (lc < 16 ? (lc - 8) * 64 : 512 + (lc - 16) * 64);
        const int kB = (lc < 8) ? lc * 64 : (lc < 16 ? 512 + (lc - 8) * 64 : (lc - 16) * 64);

        __syncthreads();
#pragma unroll
        for (int r = 0; r < 6; ++r) {               // 24 spans of 1KB
            const int s = wave * 6 + r;
            if (s < 16) {
                const int row = s * 8 + (lane >> 3);
                const int src = (lane & 7) ^ (row & 7);
                async_copy16(&As[s * 512], Eb + (size_t)(n0 + row) * 1024 + kA + src * 8);
            } else {
                const int s2 = s - 16;
                const int row = s2 * 8 + (lane >> 3);
                const int src = (lane & 7) ^ (row & 7);
                async_copy16(&Bs[s2 * 512], Wb + (size_t)(d0 + row) * 1024 + kB + src * 8);
            }
        }
        __syncthreads();

#pragma unroll
        for (int ks = 0; ks < 2; ++ks) {
            half8 af[4], bf[2];
#pragma unroll
            for (int i = 0; i < 4; ++i) {
                const int row = wm * 64 + i * 16 + lm;
                const int slot = (ks * 4 + lq) ^ (row & 7);
                af[i] = *(const half8*)&As[row * 64 + slot * 8];
            }
#pragma unroll
            for (int j = 0; j < 2; ++j) {
                const int row = wn * 32 + j * 16 + lm;
                const int slot = (ks * 4 + lq) ^ (row & 7);
                bf[j] = *(const half8*)&Bs[row * 64 + slot * 8];
            }
#pragma unroll
            for (int i = 0; i < 4; ++i)
#pragma unroll
                for (int j = 0; j < 2; ++j)
                    acc[i][j] = __builtin_amdgcn_mfma_f32_16x16x32_f16(af[i], bf[j], acc[i][j], 0, 0, 0);
        }
    }

    float bias[2];
#pragma unroll
    for (int j = 0; j < 2; ++j) bias[j] = pb[d0 + wn * 32 + j * 16 + lm];

    float nsum[16];
#pragma unroll
    for (int p = 0; p < 16; ++p) nsum[p] = 0.0f;

#pragma unroll
    for (int i = 0; i < 4; ++i) {
#pragma unroll
        for (int j = 0; j < 2; ++j) {
            const int d = d0 + wn * 32 + j * 16 + lm;
#pragma unroll
            for (int r = 0; r < 4; ++r) {
                const float v = acc[i][j][r] * 0.000244140625f + bias[j];  // 1/4096
                const int n = n0 + wm * 64 + i * 16 + lq * 4 + r;
                cb[(size_t)n * 512 + d] = v;
                Ch[(size_t)n * 512 + d] = (_Float16)(v * 64.0f);
                nsum[i * 4 + r] += v * v;
            }
        }
    }
#pragma unroll
    for (int stp = 1; stp < 16; stp <<= 1) {
#pragma unroll
        for (int p = 0; p < 16; ++p) nsum[p] += __shfl_xor(nsum[p], stp);
    }
    float myv = nsum[0];
#pragma unroll
    for (int p = 1; p < 16; ++p) if (lm == p) myv = nsum[p];
    const int n = n0 + wm * 64 + (lm >> 2) * 16 + lq * 4 + (lm & 3);
    atomicAdd(&cnorm[n], myv);
}

// ---------------------------------------------------------------------------
// K2: coarse distance GEMM (hi-only, K=512), codes on MFMA rows (A=Ch),
// z on cols (B=Zh). f = cnorm[n] - ch.zh/128. 8-code unit minima ->
// bmin[m][1024] f16. Invalid (domain-masked) blocks fill their bmin slice
// with f16-max (replaces the 16MB memset).
// ---------------------------------------------------------------------------
__global__ __launch_bounds__(256) void k_coarse(
    const _Float16* __restrict__ Zh, const _Float16* __restrict__ Ch,
    const float* __restrict__ cnorm, const int* __restrict__ dom_arr,
    _Float16* __restrict__ bmin)
{
    const int mt = blockIdx.x;          // z-tile 0..63
    const int nt = blockIdx.y;          // code-tile 0..63
    const int b = mt >> 3;
    const int dom = dom_arr[b];
    const int chunk = nt >> 4;
    const bool valid = (dom == 3) || (dom == 0 && chunk == 0) ||
                       (dom == 1 && chunk == 1) || (dom == 2 && chunk >= 2);

    const int tid = threadIdx.x;
    const int m0 = mt * 128, n0 = nt * 128;

    if (!valid) {
        const int r = tid >> 1, h = tid & 1;
        half8 v;
#pragma unroll
        for (int k = 0; k < 8; ++k) v[k] = (_Float16)65504.0f;
        *(half8*)(bmin + (size_t)(m0 + r) * 1024 + nt * 16 + h * 8) = v;
        return;
    }

    __shared__ __align__(16) _Float16 As[128 * 64];      // codes
    __shared__ __align__(16) _Float16 Bs[128 * 64];      // z
    __shared__ __align__(16) _Float16 bs[128][20];       // [m_local][unit], padded

    const int wave = tid >> 6, lane = tid & 63;
    const int wm = wave >> 1, wn = wave & 1;   // wm: code rows, wn: z cols
    const int lm = lane & 15, lq = lane >> 4;

    // hoist cnorm loads ahead of the K-loop
    float cnv[4][4];
#pragma unroll
    for (int i = 0; i < 4; ++i)
#pragma unroll
        for (int r = 0; r < 4; ++r)
            cnv[i][r] = cnorm[n0 + wm * 64 + i * 16 + lq * 4 + r];

    floatx4 acc[4][4];
#pragma unroll
    for (int i = 0; i < 4; ++i)
#pragma unroll
        for (int j = 0; j < 4; ++j) acc[i][j] = (floatx4)0.0f;

    for (int lc = 0; lc < 8; ++lc) {
        const int kk0 = lc * 64;
        __syncthreads();
#pragma unroll
        for (int r = 0; r < 4; ++r) {
            const int s = wave * 4 + r;
            const int row = s * 8 + (lane >> 3);
            const int src = (lane & 7) ^ (row & 7);
            async_copy16(&As[s * 512], Ch + (size_t)(n0 + row) * 512 + kk0 + src * 8);
            async_copy16(&Bs[s * 512], Zh + (size_t)(m0 + row) * 512 + kk0 + src * 8);
        }
        __syncthreads();

#pragma unroll
        for (int ks = 0; ks < 2; ++ks) {
            half8 af[4], bf[4];
#pragma unroll
            for (int i = 0; i < 4; ++i) {
                const int row = wm * 64 + i * 16 + lm;            // code row
                const int slot = (ks * 4 + lq) ^ (row & 7);
                af[i] = *(const half8*)&As[row * 64 + slot * 8];
            }
#pragma unroll
            for (int j = 0; j < 4; ++j) {
                const int row = wn * 64 + j * 16 + lm;            // z row
                const int slot = (ks * 4 + lq) ^ (row & 7);
                bf[j] = *(const half8*)&Bs[row * 64 + slot * 8];
            }
#pragma unroll
            for (int i = 0; i < 4; ++i)
#pragma unroll
                for (int j = 0; j < 4; ++j)
                    acc[i][j] = __builtin_amdgcn_mfma_f32_16x16x32_f16(af[i], bf[j], acc[i][j], 0, 0, 0);
        }
    }

    float um[4][4];   // [i][j] unit-min over this lane's 4 code rows
#pragma unroll
    for (int i = 0; i < 4; ++i) {
#pragma unroll
        for (int j = 0; j < 4; ++j) {
            float m01 = fminf(cnv[i][0] - acc[i][j][0] * 0.0078125f,
                              cnv[i][1] - acc[i][j][1] * 0.0078125f);
            float m23 = fminf(cnv[i][2] - acc[i][j][2] * 0.0078125f,
                              cnv[i][3] - acc[i][j][3] * 0.0078125f);
            um[i][j] = fminf(m01, m23);
        }
    }
    // combine lq pairs {0,1},{2,3} (rows p*8..p*8+7 form one 8-code unit)
#pragma unroll
    for (int i = 0; i < 4; ++i)
#pragma unroll
        for (int j = 0; j < 4; ++j)
            um[i][j] = fminf(um[i][j], __shfl_xor(um[i][j], 16));

    if ((lq & 1) == 0) {
        const int p = lq >> 1;
#pragma unroll
        for (int i = 0; i < 4; ++i)
#pragma unroll
            for (int j = 0; j < 4; ++j)
                bs[wn * 64 + j * 16 + lm][wm * 8 + i * 2 + p] = (_Float16)um[i][j];
    }
    __syncthreads();
    {   // writeout: [m][unit] -> bmin[m0+m][nt*16 + u]
        const int r = tid >> 1, h = tid & 1;
        half8 v;
#pragma unroll
        for (int k = 0; k < 8; ++k) v[k] = bs[r][h * 8 + k];
        *(half8*)(bmin + (size_t)(m0 + r) * 1024 + nt * 16 + h * 8) = v;
    }
}

// ---------------------------------------------------------------------------
// K3: refine. One wave per z-row: gmin over 1024 unit-minima; exact fp32
// rescoring of codes in units within MARGIN. Ascending scan -> first min.
// z read from the coalesced Zt copy.
// ---------------------------------------------------------------------------
__global__ __launch_bounds__(256) void k_refine(
    const float* __restrict__ Zt, const float* __restrict__ cb,
    const float* __restrict__ cnorm, const _Float16* __restrict__ bmin,
    int* __restrict__ minidx, float* __restrict__ out_idx)
{
    const int m = blockIdx.x * 4 + (threadIdx.x >> 6);
    const int lane = threadIdx.x & 63;

    const _Float16* brow = bmin + (size_t)m * 1024 + lane * 16;
    const half8 u0 = *(const half8*)brow;
    const half8 u1 = *(const half8*)(brow + 8);
    float um[16];
#pragma unroll
    for (int k = 0; k < 8; ++k) { um[k] = (float)u0[k]; um[8 + k] = (float)u1[k]; }

    float g = FLT_BIG;
#pragma unroll
    for (int k = 0; k < 16; ++k) g = fminf(g, um[k]);
#pragma unroll
    for (int s = 32; s > 0; s >>= 1) g = fminf(g, __shfl_xor(g, s));
    const float thr = g + MARGIN;

    float zr[8];
#pragma unroll
    for (int j = 0; j < 8; ++j)
        zr[j] = Zt[(size_t)m * 512 + lane + 64 * j];     // coalesced

    float bestv = FLT_BIG; int besti = 0;

    bool any = false;
#pragma unroll
    for (int k = 0; k < 16; ++k) any |= (um[k] <= thr);
    unsigned long long mask = __ballot(any);

    while (mask) {
        const int L = __ffsll(mask) - 1;
        mask &= mask - 1;
#pragma unroll
        for (int k = 0; k < 16; ++k) {
            const float uv = __shfl(um[k], L);
            if (!(uv <= thr)) continue;
            const int nbase = (L * 16 + k) * 8;
            for (int q = 0; q < 8; q += 2) {
                const float* r0 = cb + (size_t)(nbase + q) * 512 + lane;
                const float* r1 = r0 + 512;
                float d0 = 0.f, d1 = 0.f;
#pragma unroll
                for (int j = 0; j < 8; ++j) {
                    d0 += zr[j] * r0[64 * j];
                    d1 += zr[j] * r1[64 * j];
                }
#pragma unroll
                for (int s = 32; s > 0; s >>= 1) {
                    d0 += __shfl_xor(d0, s);
                    d1 += __shfl_xor(d1, s);
                }
                const float f0 = cnorm[nbase + q]     - 2.0f * d0;
                const float f1 = cnorm[nbase + q + 1] - 2.0f * d1;
                if (f0 < bestv) { bestv = f0; besti = nbase + q; }
                if (f1 < bestv) { bestv = f1; besti = nbase + q + 1; }
            }
        }
    }
    if (lane == 0) {
        minidx[m] = besti;
        out_idx[m] = (float)besti;
    }
}

// ---------------------------------------------------------------------------
// K4: z_q gather + transpose to (B,C,T) + commit loss (finalized in-kernel
// by the last block via device-scope completion counter).
// ---------------------------------------------------------------------------
#define ZQ_BLOCKS (4*16*8)
__global__ __launch_bounds__(256) void k_zq(
    const float* __restrict__ z, const float* __restrict__ cb,
    const int* __restrict__ minidx, float* __restrict__ outz,
    float* __restrict__ lossacc, unsigned int* __restrict__ donecnt,
    float* __restrict__ outloss)
{
    __shared__ float red[4];
    const int cc = blockIdx.x, tt = blockIdx.y, b = blockIdx.z;
    const int tl = threadIdx.x & 63;
    const int cg = threadIdx.x >> 6;
    const int t = tt * 64 + tl;
    const int idx = minidx[b * TT + t];
    const float* __restrict__ crow = cb + (size_t)idx * 512;

    float lsum = 0.f;
#pragma unroll 8
    for (int k = 0; k < 32; ++k) {
        const int c = cc * 128 + cg + k * 4;
        const float cv = crow[c];
        const size_t off = ((size_t)(b * ED + c)) * TT + t;
        const float zv = z[off];
        const float d = cv - zv;
        lsum += d * d;
        outz[off] = cv;
    }
#pragma unroll
    for (int off = 32; off > 0; off >>= 1) lsum += __shfl_down(lsum, off);
    if (tl == 0) red[threadIdx.x >> 6] = lsum;
    __syncthreads();
    if (threadIdx.x == 0) {
        atomicAdd(lossacc, red[0] + red[1] + red[2] + red[3]);
        __threadfence();
        const unsigned int old = atomicAdd(donecnt, 1u);
        if (old == ZQ_BLOCKS - 1) {
            const float total = atomicAdd(lossacc, 0.0f);
            *outloss = 1.25f * total / (float)(BB * ED * TT);
        }
    }
}

// ---------------------------------------------------------------------------
extern "C" void kernel_launch(void* const* d_in, const int* in_sizes, int n_in,
                              void* d_out, int out_size, void* d_ws, size_t ws_size,
                              hipStream_t stream)
{
    const float* z   = (const float*)d_in[0];
    const int*   dom = (const int*)d_in[1];
    const float* emb = (const float*)d_in[3];
    const float* pw  = (const float*)d_in[4];
    const float* pb  = (const float*)d_in[5];
    float* out = (float*)d_out;

    char* p = (char*)d_ws;
    _Float16* Zh = (_Float16*)p;            p += (size_t)MM * 512 * 2;   // 8 MB
    float*    Zt = (float*)p;               p += (size_t)MM * 512 * 4;   // 16 MB
    _Float16* Eb = (_Float16*)p;            p += (size_t)NE * 1024 * 2;  // 16 MB
    _Float16* Wb = (_Float16*)p;            p += (size_t)ED * 1024 * 2;  // 1 MB
    float*    cb = (float*)p;               p += (size_t)NE * 512 * 4;   // 16 MB
    _Float16* Ch = (_Float16*)p;            p += (size_t)NE * 512 * 2;   // 8 MB
    float* cnorm = (float*)p;               p += (size_t)NE * 4;         // 32 KB
    float* lossacc = (float*)p;             p += 4;
    unsigned int* donecnt = (unsigned int*)p; p += 4;
    _Float16* bmin = (_Float16*)p;          p += (size_t)MM * 1024 * 2;  // 16 MB
    int*   minidx = (int*)p;

    // cnorm + lossacc + donecnt are contiguous -> one memset
    hipMemsetAsync(cnorm, 0, NE * sizeof(float) + 8, stream);

    k_prep_z <<<dim3(8, 16, 8), 256, 0, stream>>>(z, Zh, Zt);
    k_prep_hl<<<(NE + ED) / 2, 256, 0, stream>>>(emb, pw, Eb, Wb);
    k_cb     <<<dim3(64, 8), 256, 0, stream>>>(Eb, Wb, pb, cb, Ch, cnorm);
    k_coarse <<<dim3(64, 64), 256, 0, stream>>>(Zh, Ch, cnorm, dom, bmin);
    k_refine <<<MM / 4, 256, 0, stream>>>(Zt, cb, cnorm, bmin, minidx, out + (size_t)NE * ED);
    k_zq     <<<dim3(4, 16, 8), 256, 0, stream>>>(z, cb, minidx, out, lossacc, donecnt,
                                                  out + (size_t)NE * ED + MM);
}

// Round 8
// 237.182 us; speedup vs baseline: 3.9701x; 1.0859x over previous
//
#include <hip/hip_runtime.h>
#include <math.h>

#define NE   8192
#define ED   512
#define BB   8
#define TT   1024
#define MM   (BB*TT)

#define FLT_BIG 3.402823466e38f
#define MARGIN  0.08f

typedef _Float16 half8 __attribute__((ext_vector_type(8)));
typedef _Float16 half4 __attribute__((ext_vector_type(4)));
typedef float    floatx4 __attribute__((ext_vector_type(4)));

typedef __attribute__((address_space(3))) unsigned int       lds_u32;
typedef const __attribute__((address_space(1))) unsigned int gbl_u32;

__device__ __forceinline__ void async_copy16(void* lds, const void* g) {
    __builtin_amdgcn_global_load_lds((gbl_u32*)(unsigned long long)g,
                                     (lds_u32*)(unsigned long long)lds,
                                     16, 0, 0);
}

// ---------------------------------------------------------------------------
// K0 (fused prep): blocks 0..1023 transpose z -> Zh (f16 4z) + Zt (fp32 rows);
// blocks 1024.. convert emb/pw -> hi/lo f16 at 64x scale.
// ---------------------------------------------------------------------------
__global__ __launch_bounds__(256) void k_prep(
    const float* __restrict__ z, const float* __restrict__ emb,
    const float* __restrict__ pw, _Float16* __restrict__ Zh,
    float* __restrict__ Zt, _Float16* __restrict__ Eb,
    _Float16* __restrict__ Wb)
{
    const int bid = blockIdx.x;
    const int tid = threadIdx.x;
    if (bid < 1024) {
        __shared__ float T[64][68];
        const int ct = bid & 7, tt = (bid >> 3) & 15, b = bid >> 7;
        const int f4 = tid & 15;
        const int c0 = tid >> 4;
#pragma unroll
        for (int r = 0; r < 4; ++r) {
            const int c = c0 + r * 16;
            const float4 v = *(const float4*)(z + ((size_t)(b * ED + ct * 64 + c)) * TT + tt * 64 + f4 * 4);
            T[f4*4+0][c] = v.x; T[f4*4+1][c] = v.y;
            T[f4*4+2][c] = v.z; T[f4*4+3][c] = v.w;
        }
        __syncthreads();
        {   // f16 hi write
            const int tl = tid >> 2, q = tid & 3;
            const size_t m = (size_t)b * TT + tt * 64 + tl;
            _Float16* outh = Zh + m * 512 + ct * 64 + q * 16;
#pragma unroll
            for (int g = 0; g < 2; ++g) {
                half8 hv;
#pragma unroll
                for (int jj = 0; jj < 8; ++jj)
                    hv[jj] = (_Float16)(4.0f * T[tl][q*16 + g*8 + jj]);
                *(half8*)(outh + g * 8) = hv;
            }
        }
        {   // fp32 transposed write
            const int tl2 = tid >> 4;
            const int c4 = (tid & 15) * 4;
#pragma unroll
            for (int it = 0; it < 4; ++it) {
                const int t_local = tl2 + it * 16;
                const float4 v = *(const float4*)&T[t_local][c4];
                *(float4*)(Zt + ((size_t)b * TT + tt * 64 + t_local) * 512 + ct * 64 + c4) = v;
            }
        }
    } else {
        const int g = (bid - 1024) * 256 + tid;
        const int row = g >> 7, c4 = (g & 127) * 4;
        const float* src;
        _Float16* dst;
        if (row < NE) { src = emb + (size_t)row * 512;        dst = Eb + (size_t)row * 1024; }
        else          { src = pw + (size_t)(row - NE) * 512;  dst = Wb + (size_t)(row - NE) * 1024; }
        const float4 v = *(const float4*)(src + c4);
        half4 h, l;
        const float s[4] = {v.x * 64.0f, v.y * 64.0f, v.z * 64.0f, v.w * 64.0f};
#pragma unroll
        for (int j = 0; j < 4; ++j) {
            const _Float16 hh = (_Float16)s[j];
            h[j] = hh;
            l[j] = (_Float16)(s[j] - (float)hh);
        }
        *(half4*)(dst + c4) = h;
        *(half4*)(dst + 512 + c4) = l;
    }
}

// ---------------------------------------------------------------------------
// K1: codebook GEMM, fused-term staging: each 64-k chunk loads Eh,El,Wh,Wl
// ONCE and runs the 3 hi/lo MFMA terms from it (8 iters vs 24). One
// contiguous LDS array (S) indexed by bufi*8192 — a pointer ARRAY of
// distinct __shared__ objects fails gfx950 codegen (addrspacecast in
// static initializer). Tile 128n x 128d, 512 threads = 8 waves of 64x32.
// ---------------------------------------------------------------------------
#define S_AH 0
#define S_AL 8192
#define S_BH 16384
#define S_BL 24576
__global__ __launch_bounds__(512) void k_cb(
    const _Float16* __restrict__ Eb, const _Float16* __restrict__ Wb,
    const float* __restrict__ pb, float* __restrict__ cb,
    _Float16* __restrict__ Ch, float* __restrict__ cnorm)
{
    __shared__ __align__(16) _Float16 S[4 * 128 * 64];   // Ah|Al|Bh|Bl

    const int tid = threadIdx.x;
    const int wave = tid >> 6, lane = tid & 63;
    const int n0 = blockIdx.x * 128, d0 = blockIdx.y * 128;
    const int wm = wave >> 2, wn = wave & 3;          // 2x4 waves -> 64x32 each
    const int lm = lane & 15, lq = lane >> 4;

    floatx4 acc[4][2];
#pragma unroll
    for (int i = 0; i < 4; ++i)
#pragma unroll
        for (int j = 0; j < 2; ++j) acc[i][j] = (floatx4)0.0f;

    for (int lc = 0; lc < 8; ++lc) {
        const int kc = lc * 64;
        __syncthreads();
#pragma unroll
        for (int r = 0; r < 8; ++r) {               // 64 spans of 1KB
            const int s = wave * 8 + r;
            const int bufi = s >> 4, s2 = s & 15;
            const int row = s2 * 8 + (lane >> 3);
            const int src = (lane & 7) ^ (row & 7);
            const _Float16* gsrc;
            if (bufi == 0)      gsrc = Eb + (size_t)(n0 + row) * 1024 + kc + src * 8;
            else if (bufi == 1) gsrc = Eb + (size_t)(n0 + row) * 1024 + 512 + kc + src * 8;
            else if (bufi == 2) gsrc = Wb + (size_t)(d0 + row) * 1024 + kc + src * 8;
            else                gsrc = Wb + (size_t)(d0 + row) * 1024 + 512 + kc + src * 8;
            async_copy16(&S[bufi * 8192 + s2 * 512], gsrc);
        }
        __syncthreads();

#pragma unroll
        for (int ks = 0; ks < 2; ++ks) {
            half8 ah[4], al[4], bh[2], bl[2];
#pragma unroll
            for (int i = 0; i < 4; ++i) {
                const int row = wm * 64 + i * 16 + lm;
                const int slot = (ks * 4 + lq) ^ (row & 7);
                ah[i] = *(const half8*)&S[S_AH + row * 64 + slot * 8];
                al[i] = *(const half8*)&S[S_AL + row * 64 + slot * 8];
            }
#pragma unroll
            for (int j = 0; j < 2; ++j) {
                const int row = wn * 32 + j * 16 + lm;
                const int slot = (ks * 4 + lq) ^ (row & 7);
                bh[j] = *(const half8*)&S[S_BH + row * 64 + slot * 8];
                bl[j] = *(const half8*)&S[S_BL + row * 64 + slot * 8];
            }
#pragma unroll
            for (int i = 0; i < 4; ++i)
#pragma unroll
                for (int j = 0; j < 2; ++j) {
                    acc[i][j] = __builtin_amdgcn_mfma_f32_16x16x32_f16(ah[i], bh[j], acc[i][j], 0, 0, 0);
                    acc[i][j] = __builtin_amdgcn_mfma_f32_16x16x32_f16(ah[i], bl[j], acc[i][j], 0, 0, 0);
                    acc[i][j] = __builtin_amdgcn_mfma_f32_16x16x32_f16(al[i], bh[j], acc[i][j], 0, 0, 0);
                }
        }
    }

    float bias[2];
#pragma unroll
    for (int j = 0; j < 2; ++j) bias[j] = pb[d0 + wn * 32 + j * 16 + lm];

    float nsum[16];
#pragma unroll
    for (int p = 0; p < 16; ++p) nsum[p] = 0.0f;

#pragma unroll
    for (int i = 0; i < 4; ++i) {
#pragma unroll
        for (int j = 0; j < 2; ++j) {
            const int d = d0 + wn * 32 + j * 16 + lm;
#pragma unroll
            for (int r = 0; r < 4; ++r) {
                const float v = acc[i][j][r] * 0.000244140625f + bias[j];  // 1/4096
                const int n = n0 + wm * 64 + i * 16 + lq * 4 + r;
                cb[(size_t)n * 512 + d] = v;
                Ch[(size_t)n * 512 + d] = (_Float16)(v * 64.0f);
                nsum[i * 4 + r] += v * v;
            }
        }
    }
#pragma unroll
    for (int stp = 1; stp < 16; stp <<= 1) {
#pragma unroll
        for (int p = 0; p < 16; ++p) nsum[p] += __shfl_xor(nsum[p], stp);
    }
    float myv = nsum[0];
#pragma unroll
    for (int p = 1; p < 16; ++p) if (lm == p) myv = nsum[p];
    const int n = n0 + wm * 64 + (lm >> 2) * 16 + lq * 4 + (lm & 3);
    atomicAdd(&cnorm[n], myv);
}

// ---------------------------------------------------------------------------
// K2: coarse distance GEMM (hi-only, K=512), codes on MFMA rows (A=Ch),
// z on cols (B=Zh). f = cnorm[n] - ch.zh/128. 8-code unit minima ->
// bmin[m][1024] f16. Invalid blocks fill their slice with f16-max.
// (cnorm loads kept in the EPILOGUE: hoisting them cost VGPR 84->96 and
//  15 us in round 6 — latency-bound kernel, occupancy matters more.)
// ---------------------------------------------------------------------------
__global__ __launch_bounds__(256) void k_coarse(
    const _Float16* __restrict__ Zh, const _Float16* __restrict__ Ch,
    const float* __restrict__ cnorm, const int* __restrict__ dom_arr,
    _Float16* __restrict__ bmin)
{
    const int mt = blockIdx.x;          // z-tile 0..63
    const int nt = blockIdx.y;          // code-tile 0..63
    const int b = mt >> 3;
    const int dom = dom_arr[b];
    const int chunk = nt >> 4;
    const bool valid = (dom == 3) || (dom == 0 && chunk == 0) ||
                       (dom == 1 && chunk == 1) || (dom == 2 && chunk >= 2);

    const int tid = threadIdx.x;
    const int m0 = mt * 128, n0 = nt * 128;

    if (!valid) {
        const int r = tid >> 1, h = tid & 1;
        half8 v;
#pragma unroll
        for (int k = 0; k < 8; ++k) v[k] = (_Float16)65504.0f;
        *(half8*)(bmin + (size_t)(m0 + r) * 1024 + nt * 16 + h * 8) = v;
        return;
    }

    __shared__ __align__(16) _Float16 As[128 * 64];      // codes
    __shared__ __align__(16) _Float16 Bs[128 * 64];      // z
    __shared__ __align__(16) _Float16 bs[128][20];       // [m_local][unit], padded

    const int wave = tid >> 6, lane = tid & 63;
    const int wm = wave >> 1, wn = wave & 1;   // wm: code rows, wn: z cols
    const int lm = lane & 15, lq = lane >> 4;

    floatx4 acc[4][4];
#pragma unroll
    for (int i = 0; i < 4; ++i)
#pragma unroll
        for (int j = 0; j < 4; ++j) acc[i][j] = (floatx4)0.0f;

    for (int lc = 0; lc < 8; ++lc) {
        const int kk0 = lc * 64;
        __syncthreads();
#pragma unroll
        for (int r = 0; r < 4; ++r) {
            const int s = wave * 4 + r;
            const int row = s * 8 + (lane >> 3);
            const int src = (lane & 7) ^ (row & 7);
            async_copy16(&As[s * 512], Ch + (size_t)(n0 + row) * 512 + kk0 + src * 8);
            async_copy16(&Bs[s * 512], Zh + (size_t)(m0 + row) * 512 + kk0 + src * 8);
        }
        __syncthreads();

#pragma unroll
        for (int ks = 0; ks < 2; ++ks) {
            half8 af[4], bf[4];
#pragma unroll
            for (int i = 0; i < 4; ++i) {
                const int row = wm * 64 + i * 16 + lm;            // code row
                const int slot = (ks * 4 + lq) ^ (row & 7);
                af[i] = *(const half8*)&As[row * 64 + slot * 8];
            }
#pragma unroll
            for (int j = 0; j < 4; ++j) {
                const int row = wn * 64 + j * 16 + lm;            // z row
                const int slot = (ks * 4 + lq) ^ (row & 7);
                bf[j] = *(const half8*)&Bs[row * 64 + slot * 8];
            }
#pragma unroll
            for (int i = 0; i < 4; ++i)
#pragma unroll
                for (int j = 0; j < 4; ++j)
                    acc[i][j] = __builtin_amdgcn_mfma_f32_16x16x32_f16(af[i], bf[j], acc[i][j], 0, 0, 0);
        }
    }

    // D layout: row (code) = wm*64 + i*16 + lq*4 + r, col (z) = wn*64 + j*16 + lm
    float cnv[4][4];
#pragma unroll
    for (int i = 0; i < 4; ++i)
#pragma unroll
        for (int r = 0; r < 4; ++r)
            cnv[i][r] = cnorm[n0 + wm * 64 + i * 16 + lq * 4 + r];

    float um[4][4];
#pragma unroll
    for (int i = 0; i < 4; ++i) {
#pragma unroll
        for (int j = 0; j < 4; ++j) {
            float m01 = fminf(cnv[i][0] - acc[i][j][0] * 0.0078125f,
                              cnv[i][1] - acc[i][j][1] * 0.0078125f);
            float m23 = fminf(cnv[i][2] - acc[i][j][2] * 0.0078125f,
                              cnv[i][3] - acc[i][j][3] * 0.0078125f);
            um[i][j] = fminf(m01, m23);
        }
    }
#pragma unroll
    for (int i = 0; i < 4; ++i)
#pragma unroll
        for (int j = 0; j < 4; ++j)
            um[i][j] = fminf(um[i][j], __shfl_xor(um[i][j], 16));

    if ((lq & 1) == 0) {
        const int p = lq >> 1;
#pragma unroll
        for (int i = 0; i < 4; ++i)
#pragma unroll
            for (int j = 0; j < 4; ++j)
                bs[wn * 64 + j * 16 + lm][wm * 8 + i * 2 + p] = (_Float16)um[i][j];
    }
    __syncthreads();
    {
        const int r = tid >> 1, h = tid & 1;
        half8 v;
#pragma unroll
        for (int k = 0; k < 8; ++k) v[k] = bs[r][h * 8 + k];
        *(half8*)(bmin + (size_t)(m0 + r) * 1024 + nt * 16 + h * 8) = v;
    }
}

// ---------------------------------------------------------------------------
// K3: refine. One wave per z-row: gmin over 1024 unit-minima; exact fp32
// rescoring of codes in units within MARGIN. Ascending scan -> first min.
// ---------------------------------------------------------------------------
__global__ __launch_bounds__(256) void k_refine(
    const float* __restrict__ Zt, const float* __restrict__ cb,
    const float* __restrict__ cnorm, const _Float16* __restrict__ bmin,
    int* __restrict__ minidx, float* __restrict__ out_idx)
{
    const int m = blockIdx.x * 4 + (threadIdx.x >> 6);
    const int lane = threadIdx.x & 63;

    const _Float16* brow = bmin + (size_t)m * 1024 + lane * 16;
    const half8 u0 = *(const half8*)brow;
    const half8 u1 = *(const half8*)(brow + 8);
    float um[16];
#pragma unroll
    for (int k = 0; k < 8; ++k) { um[k] = (float)u0[k]; um[8 + k] = (float)u1[k]; }

    float g = FLT_BIG;
#pragma unroll
    for (int k = 0; k < 16; ++k) g = fminf(g, um[k]);
#pragma unroll
    for (int s = 32; s > 0; s >>= 1) g = fminf(g, __shfl_xor(g, s));
    const float thr = g + MARGIN;

    float zr[8];
#pragma unroll
    for (int j = 0; j < 8; ++j)
        zr[j] = Zt[(size_t)m * 512 + lane + 64 * j];

    float bestv = FLT_BIG; int besti = 0;

    bool any = false;
#pragma unroll
    for (int k = 0; k < 16; ++k) any |= (um[k] <= thr);
    unsigned long long mask = __ballot(any);

    while (mask) {
        const int L = __ffsll(mask) - 1;
        mask &= mask - 1;
#pragma unroll
        for (int k = 0; k < 16; ++k) {
            const float uv = __shfl(um[k], L);
            if (!(uv <= thr)) continue;
            const int nbase = (L * 16 + k) * 8;
            for (int q = 0; q < 8; q += 2) {
                const float* r0 = cb + (size_t)(nbase + q) * 512 + lane;
                const float* r1 = r0 + 512;
                float d0 = 0.f, d1 = 0.f;
#pragma unroll
                for (int j = 0; j < 8; ++j) {
                    d0 += zr[j] * r0[64 * j];
                    d1 += zr[j] * r1[64 * j];
                }
#pragma unroll
                for (int s = 32; s > 0; s >>= 1) {
                    d0 += __shfl_xor(d0, s);
                    d1 += __shfl_xor(d1, s);
                }
                const float f0 = cnorm[nbase + q]     - 2.0f * d0;
                const float f1 = cnorm[nbase + q + 1] - 2.0f * d1;
                if (f0 < bestv) { bestv = f0; besti = nbase + q; }
                if (f1 < bestv) { bestv = f1; besti = nbase + q + 1; }
            }
        }
    }
    if (lane == 0) {
        minidx[m] = besti;
        out_idx[m] = (float)besti;
    }
}

// ---------------------------------------------------------------------------
// K4: z_q gather + transpose to (B,C,T) + commit loss (finalized in-kernel).
// ---------------------------------------------------------------------------
#define ZQ_BLOCKS (4*16*8)
__global__ __launch_bounds__(256) void k_zq(
    const float* __restrict__ z, const float* __restrict__ cb,
    const int* __restrict__ minidx, float* __restrict__ outz,
    float* __restrict__ lossacc, unsigned int* __restrict__ donecnt,
    float* __restrict__ outloss)
{
    __shared__ float red[4];
    const int cc = blockIdx.x, tt = blockIdx.y, b = blockIdx.z;
    const int tl = threadIdx.x & 63;
    const int cg = threadIdx.x >> 6;
    const int t = tt * 64 + tl;
    const int idx = minidx[b * TT + t];
    const float* __restrict__ crow = cb + (size_t)idx * 512;

    float lsum = 0.f;
#pragma unroll 8
    for (int k = 0; k < 32; ++k) {
        const int c = cc * 128 + cg + k * 4;
        const float cv = crow[c];
        const size_t off = ((size_t)(b * ED + c)) * TT + t;
        const float zv = z[off];
        const float d = cv - zv;
        lsum += d * d;
        outz[off] = cv;
    }
#pragma unroll
    for (int off = 32; off > 0; off >>= 1) lsum += __shfl_down(lsum, off);
    if (tl == 0) red[threadIdx.x >> 6] = lsum;
    __syncthreads();
    if (threadIdx.x == 0) {
        atomicAdd(lossacc, red[0] + red[1] + red[2] + red[3]);
        __threadfence();
        const unsigned int old = atomicAdd(donecnt, 1u);
        if (old == ZQ_BLOCKS - 1) {
            const float total = atomicAdd(lossacc, 0.0f);
            *outloss = 1.25f * total / (float)(BB * ED * TT);
        }
    }
}

// ---------------------------------------------------------------------------
extern "C" void kernel_launch(void* const* d_in, const int* in_sizes, int n_in,
                              void* d_out, int out_size, void* d_ws, size_t ws_size,
                              hipStream_t stream)
{
    const float* z   = (const float*)d_in[0];
    const int*   dom = (const int*)d_in[1];
    const float* emb = (const float*)d_in[3];
    const float* pw  = (const float*)d_in[4];
    const float* pb  = (const float*)d_in[5];
    float* out = (float*)d_out;

    char* p = (char*)d_ws;
    _Float16* Zh = (_Float16*)p;            p += (size_t)MM * 512 * 2;   // 8 MB
    float*    Zt = (float*)p;               p += (size_t)MM * 512 * 4;   // 16 MB
    _Float16* Eb = (_Float16*)p;            p += (size_t)NE * 1024 * 2;  // 16 MB
    _Float16* Wb = (_Float16*)p;            p += (size_t)ED * 1024 * 2;  // 1 MB
    float*    cb = (float*)p;               p += (size_t)NE * 512 * 4;   // 16 MB
    _Float16* Ch = (_Float16*)p;            p += (size_t)NE * 512 * 2;   // 8 MB
    float* cnorm = (float*)p;               p += (size_t)NE * 4;         // 32 KB
    float* lossacc = (float*)p;             p += 4;
    unsigned int* donecnt = (unsigned int*)p; p += 4;
    _Float16* bmin = (_Float16*)p;          p += (size_t)MM * 1024 * 2;  // 16 MB
    int*   minidx = (int*)p;

    (void)hipMemsetAsync(cnorm, 0, NE * sizeof(float) + 8, stream);

    k_prep   <<<1024 + (NE + ED) / 2, 256, 0, stream>>>(z, emb, pw, Zh, Zt, Eb, Wb);
    k_cb     <<<dim3(64, 4), 512, 0, stream>>>(Eb, Wb, pb, cb, Ch, cnorm);
    k_coarse <<<dim3(64, 64), 256, 0, stream>>>(Zh, Ch, cnorm, dom, bmin);
    k_refine <<<MM / 4, 256, 0, stream>>>(Zt, cb, cnorm, bmin, minidx, out + (size_t)NE * ED);
    k_zq     <<<dim3(4, 16, 8), 256, 0, stream>>>(z, cb, minidx, out, lossacc, donecnt,
                                                  out + (size_t)NE * ED + MM);
}

// Round 9
// 222.181 us; speedup vs baseline: 4.2381x; 1.0675x over previous
//
#include <hip/hip_runtime.h>
#include <math.h>

#define NE   8192
#define ED   512
#define BB   8
#define TT   1024
#define MM   (BB*TT)

#define FLT_BIG 3.402823466e38f
#define MARGIN  0.08f

typedef _Float16 half8 __attribute__((ext_vector_type(8)));
typedef _Float16 half4 __attribute__((ext_vector_type(4)));
typedef float    floatx4 __attribute__((ext_vector_type(4)));

typedef __attribute__((address_space(3))) unsigned int       lds_u32;
typedef const __attribute__((address_space(1))) unsigned int gbl_u32;

__device__ __forceinline__ void async_copy16(void* lds, const void* g) {
    __builtin_amdgcn_global_load_lds((gbl_u32*)(unsigned long long)g,
                                     (lds_u32*)(unsigned long long)lds,
                                     16, 0, 0);
}

// ---------------------------------------------------------------------------
// K0 (fused prep): blocks 0..1023 transpose z -> Zh (f16 4z) + Zt (fp32 rows);
// blocks 1024..5375 convert emb/pw -> hi/lo f16; blocks 5376..5384 zero
// cnorm/lossacc/donecnt (replaces the memset dispatch; stream-ordered
// before k_cb's atomics).
// ---------------------------------------------------------------------------
__global__ __launch_bounds__(256) void k_prep(
    const float* __restrict__ z, const float* __restrict__ emb,
    const float* __restrict__ pw, _Float16* __restrict__ Zh,
    float* __restrict__ Zt, _Float16* __restrict__ Eb,
    _Float16* __restrict__ Wb, float* __restrict__ cnorm)
{
    const int bid = blockIdx.x;
    const int tid = threadIdx.x;
    if (bid < 1024) {
        __shared__ float T[64][68];
        const int ct = bid & 7, tt = (bid >> 3) & 15, b = bid >> 7;
        const int f4 = tid & 15;
        const int c0 = tid >> 4;
#pragma unroll
        for (int r = 0; r < 4; ++r) {
            const int c = c0 + r * 16;
            const float4 v = *(const float4*)(z + ((size_t)(b * ED + ct * 64 + c)) * TT + tt * 64 + f4 * 4);
            T[f4*4+0][c] = v.x; T[f4*4+1][c] = v.y;
            T[f4*4+2][c] = v.z; T[f4*4+3][c] = v.w;
        }
        __syncthreads();
        {   // f16 hi write
            const int tl = tid >> 2, q = tid & 3;
            const size_t m = (size_t)b * TT + tt * 64 + tl;
            _Float16* outh = Zh + m * 512 + ct * 64 + q * 16;
#pragma unroll
            for (int g = 0; g < 2; ++g) {
                half8 hv;
#pragma unroll
                for (int jj = 0; jj < 8; ++jj)
                    hv[jj] = (_Float16)(4.0f * T[tl][q*16 + g*8 + jj]);
                *(half8*)(outh + g * 8) = hv;
            }
        }
        {   // fp32 transposed write
            const int tl2 = tid >> 4;
            const int c4 = (tid & 15) * 4;
#pragma unroll
            for (int it = 0; it < 4; ++it) {
                const int t_local = tl2 + it * 16;
                const float4 v = *(const float4*)&T[t_local][c4];
                *(float4*)(Zt + ((size_t)b * TT + tt * 64 + t_local) * 512 + ct * 64 + c4) = v;
            }
        }
    } else if (bid < 5376) {
        const int g = (bid - 1024) * 256 + tid;
        const int row = g >> 7, c4 = (g & 127) * 4;
        const float* src;
        _Float16* dst;
        if (row < NE) { src = emb + (size_t)row * 512;        dst = Eb + (size_t)row * 1024; }
        else          { src = pw + (size_t)(row - NE) * 512;  dst = Wb + (size_t)(row - NE) * 1024; }
        const float4 v = *(const float4*)(src + c4);
        half4 h, l;
        const float s[4] = {v.x * 64.0f, v.y * 64.0f, v.z * 64.0f, v.w * 64.0f};
#pragma unroll
        for (int j = 0; j < 4; ++j) {
            const _Float16 hh = (_Float16)s[j];
            h[j] = hh;
            l[j] = (_Float16)(s[j] - (float)hh);
        }
        *(half4*)(dst + c4) = h;
        *(half4*)(dst + 512 + c4) = l;
    } else {
        const int zidx = bid - 5376;          // 0..8
        if (zidx < 8) {
            ((float4*)cnorm)[zidx * 256 + tid] = make_float4(0.f, 0.f, 0.f, 0.f);
        } else if (tid == 0) {
            cnorm[NE] = 0.0f;                 // lossacc
            ((unsigned int*)cnorm)[NE + 1] = 0u;  // donecnt
        }
    }
}

// ---------------------------------------------------------------------------
// K1: codebook GEMM, fused-term staging (Eh,El,Wh,Wl loaded once per 64-k
// chunk; 3 hi/lo MFMA terms). Retiled 128n x 64d, 256 threads, grid (64,8)
// = 512 blocks (~3 blocks/CU; the old (64,4)x512thr grid was 1 block/CU —
// no cross-block latency hiding). LDS 48 KB single array.
// ---------------------------------------------------------------------------
#define S_AH 0
#define S_AL 8192
#define S_BH 16384
#define S_BL 20480
__global__ __launch_bounds__(256) void k_cb(
    const _Float16* __restrict__ Eb, const _Float16* __restrict__ Wb,
    const float* __restrict__ pb, float* __restrict__ cb,
    _Float16* __restrict__ Ch, float* __restrict__ cnorm)
{
    __shared__ __align__(16) _Float16 S[24576];   // Ah(16K)|Al(16K)|Bh(8K)|Bl(8K) bytes

    const int tid = threadIdx.x;
    const int wave = tid >> 6, lane = tid & 63;
    const int n0 = blockIdx.x * 128, d0 = blockIdx.y * 64;
    const int wm = wave >> 1, wn = wave & 1;      // 2x2 waves -> 64 codes x 32 d
    const int lm = lane & 15, lq = lane >> 4;

    floatx4 acc[4][2];
#pragma unroll
    for (int i = 0; i < 4; ++i)
#pragma unroll
        for (int j = 0; j < 2; ++j) acc[i][j] = (floatx4)0.0f;

    for (int lc = 0; lc < 8; ++lc) {
        const int kc = lc * 64;
        __syncthreads();
#pragma unroll
        for (int r = 0; r < 12; ++r) {            // 48 spans of 1KB
            const int s = wave * 12 + r;
            const int row8 = lane >> 3;
            const int srcx = lane & 7;
            if (s < 16) {
                const int row = s * 8 + row8;
                const int src = srcx ^ (row & 7);
                async_copy16(&S[S_AH + s * 512], Eb + (size_t)(n0 + row) * 1024 + kc + src * 8);
            } else if (s < 32) {
                const int s2 = s - 16;
                const int row = s2 * 8 + row8;
                const int src = srcx ^ (row & 7);
                async_copy16(&S[S_AL + s2 * 512], Eb + (size_t)(n0 + row) * 1024 + 512 + kc + src * 8);
            } else if (s < 40) {
                const int s2 = s - 32;
                const int row = s2 * 8 + row8;
                const int src = srcx ^ (row & 7);
                async_copy16(&S[S_BH + s2 * 512], Wb + (size_t)(d0 + row) * 1024 + kc + src * 8);
            } else {
                const int s2 = s - 40;
                const int row = s2 * 8 + row8;
                const int src = srcx ^ (row & 7);
                async_copy16(&S[S_BL + s2 * 512], Wb + (size_t)(d0 + row) * 1024 + 512 + kc + src * 8);
            }
        }
        __syncthreads();

#pragma unroll
        for (int ks = 0; ks < 2; ++ks) {
            half8 ah[4], al[4], bh[2], bl[2];
#pragma unroll
            for (int i = 0; i < 4; ++i) {
                const int row = wm * 64 + i * 16 + lm;
                const int slot = (ks * 4 + lq) ^ (row & 7);
                ah[i] = *(const half8*)&S[S_AH + row * 64 + slot * 8];
                al[i] = *(const half8*)&S[S_AL + row * 64 + slot * 8];
            }
#pragma unroll
            for (int j = 0; j < 2; ++j) {
                const int row = wn * 32 + j * 16 + lm;
                const int slot = (ks * 4 + lq) ^ (row & 7);
                bh[j] = *(const half8*)&S[S_BH + row * 64 + slot * 8];
                bl[j] = *(const half8*)&S[S_BL + row * 64 + slot * 8];
            }
#pragma unroll
            for (int i = 0; i < 4; ++i)
#pragma unroll
                for (int j = 0; j < 2; ++j) {
                    acc[i][j] = __builtin_amdgcn_mfma_f32_16x16x32_f16(ah[i], bh[j], acc[i][j], 0, 0, 0);
                    acc[i][j] = __builtin_amdgcn_mfma_f32_16x16x32_f16(ah[i], bl[j], acc[i][j], 0, 0, 0);
                    acc[i][j] = __builtin_amdgcn_mfma_f32_16x16x32_f16(al[i], bh[j], acc[i][j], 0, 0, 0);
                }
        }
    }

    float bias[2];
#pragma unroll
    for (int j = 0; j < 2; ++j) bias[j] = pb[d0 + wn * 32 + j * 16 + lm];

    float nsum[16];
#pragma unroll
    for (int p = 0; p < 16; ++p) nsum[p] = 0.0f;

#pragma unroll
    for (int i = 0; i < 4; ++i) {
#pragma unroll
        for (int j = 0; j < 2; ++j) {
            const int d = d0 + wn * 32 + j * 16 + lm;
#pragma unroll
            for (int r = 0; r < 4; ++r) {
                const float v = acc[i][j][r] * 0.000244140625f + bias[j];  // 1/4096
                const int n = n0 + wm * 64 + i * 16 + lq * 4 + r;
                cb[(size_t)n * 512 + d] = v;
                Ch[(size_t)n * 512 + d] = (_Float16)(v * 64.0f);
                nsum[i * 4 + r] += v * v;
            }
        }
    }
#pragma unroll
    for (int stp = 1; stp < 16; stp <<= 1) {
#pragma unroll
        for (int p = 0; p < 16; ++p) nsum[p] += __shfl_xor(nsum[p], stp);
    }
    float myv = nsum[0];
#pragma unroll
    for (int p = 1; p < 16; ++p) if (lm == p) myv = nsum[p];
    const int n = n0 + wm * 64 + (lm >> 2) * 16 + lq * 4 + (lm & 3);
    atomicAdd(&cnorm[n], myv);
}

// ---------------------------------------------------------------------------
// K2: coarse distance GEMM (hi-only, K=512), codes on MFMA rows (A=Ch),
// z on cols (B=Zh). cnorm tile staged into LDS (one masked global_load_lds)
// instead of 16 scattered epilogue loads/thread. 8-code unit minima ->
// bmin[m][1024] f16; invalid blocks fill their slice with f16-max.
// ---------------------------------------------------------------------------
__global__ __launch_bounds__(256) void k_coarse(
    const _Float16* __restrict__ Zh, const _Float16* __restrict__ Ch,
    const float* __restrict__ cnorm, const int* __restrict__ dom_arr,
    _Float16* __restrict__ bmin)
{
    const int mt = blockIdx.x;          // z-tile 0..63
    const int nt = blockIdx.y;          // code-tile 0..63
    const int b = mt >> 3;
    const int dom = dom_arr[b];
    const int chunk = nt >> 4;
    const bool valid = (dom == 3) || (dom == 0 && chunk == 0) ||
                       (dom == 1 && chunk == 1) || (dom == 2 && chunk >= 2);

    const int tid = threadIdx.x;
    const int m0 = mt * 128, n0 = nt * 128;

    if (!valid) {
        const int r = tid >> 1, h = tid & 1;
        half8 v;
#pragma unroll
        for (int k = 0; k < 8; ++k) v[k] = (_Float16)65504.0f;
        *(half8*)(bmin + (size_t)(m0 + r) * 1024 + nt * 16 + h * 8) = v;
        return;
    }

    __shared__ __align__(16) _Float16 As[128 * 64];      // codes
    __shared__ __align__(16) _Float16 Bs[128 * 64];      // z
    __shared__ __align__(16) _Float16 bs[128][20];       // [m_local][unit], padded
    __shared__ __align__(16) float cnLds[128];

    const int wave = tid >> 6, lane = tid & 63;
    const int wm = wave >> 1, wn = wave & 1;   // wm: code rows, wn: z cols
    const int lm = lane & 15, lq = lane >> 4;

    floatx4 acc[4][4];
#pragma unroll
    for (int i = 0; i < 4; ++i)
#pragma unroll
        for (int j = 0; j < 4; ++j) acc[i][j] = (floatx4)0.0f;

    for (int lc = 0; lc < 8; ++lc) {
        const int kk0 = lc * 64;
        __syncthreads();
#pragma unroll
        for (int r = 0; r < 4; ++r) {
            const int s = wave * 4 + r;
            const int row = s * 8 + (lane >> 3);
            const int src = (lane & 7) ^ (row & 7);
            async_copy16(&As[s * 512], Ch + (size_t)(n0 + row) * 512 + kk0 + src * 8);
            async_copy16(&Bs[s * 512], Zh + (size_t)(m0 + row) * 512 + kk0 + src * 8);
        }
        if (lc == 0 && wave == 0 && lane < 32)
            async_copy16(&cnLds[0], cnorm + n0 + lane * 4);
        __syncthreads();

#pragma unroll
        for (int ks = 0; ks < 2; ++ks) {
            half8 af[4], bf[4];
#pragma unroll
            for (int i = 0; i < 4; ++i) {
                const int row = wm * 64 + i * 16 + lm;            // code row
                const int slot = (ks * 4 + lq) ^ (row & 7);
                af[i] = *(const half8*)&As[row * 64 + slot * 8];
            }
#pragma unroll
            for (int j = 0; j < 4; ++j) {
                const int row = wn * 64 + j * 16 + lm;            // z row
                const int slot = (ks * 4 + lq) ^ (row & 7);
                bf[j] = *(const half8*)&Bs[row * 64 + slot * 8];
            }
#pragma unroll
            for (int i = 0; i < 4; ++i)
#pragma unroll
                for (int j = 0; j < 4; ++j)
                    acc[i][j] = __builtin_amdgcn_mfma_f32_16x16x32_f16(af[i], bf[j], acc[i][j], 0, 0, 0);
        }
    }

    // D layout: row (code) = wm*64 + i*16 + lq*4 + r, col (z) = wn*64 + j*16 + lm
    float cnv[4][4];
#pragma unroll
    for (int i = 0; i < 4; ++i)
#pragma unroll
        for (int r = 0; r < 4; ++r)
            cnv[i][r] = cnLds[wm * 64 + i * 16 + lq * 4 + r];

    float um[4][4];
#pragma unroll
    for (int i = 0; i < 4; ++i) {
#pragma unroll
        for (int j = 0; j < 4; ++j) {
            float m01 = fminf(cnv[i][0] - acc[i][j][0] * 0.0078125f,
                              cnv[i][1] - acc[i][j][1] * 0.0078125f);
            float m23 = fminf(cnv[i][2] - acc[i][j][2] * 0.0078125f,
                              cnv[i][3] - acc[i][j][3] * 0.0078125f);
            um[i][j] = fminf(m01, m23);
        }
    }
#pragma unroll
    for (int i = 0; i < 4; ++i)
#pragma unroll
        for (int j = 0; j < 4; ++j)
            um[i][j] = fminf(um[i][j], __shfl_xor(um[i][j], 16));

    if ((lq & 1) == 0) {
        const int p = lq >> 1;
#pragma unroll
        for (int i = 0; i < 4; ++i)
#pragma unroll
            for (int j = 0; j < 4; ++j)
                bs[wn * 64 + j * 16 + lm][wm * 8 + i * 2 + p] = (_Float16)um[i][j];
    }
    __syncthreads();
    {
        const int r = tid >> 1, h = tid & 1;
        half8 v;
#pragma unroll
        for (int k = 0; k < 8; ++k) v[k] = bs[r][h * 8 + k];
        *(half8*)(bmin + (size_t)(m0 + r) * 1024 + nt * 16 + h * 8) = v;
    }
}

// ---------------------------------------------------------------------------
// K3: refine. One wave per z-row: gmin over 1024 unit-minima; exact fp32
// rescoring of codes in units within MARGIN. Ascending scan -> first min.
// ---------------------------------------------------------------------------
__global__ __launch_bounds__(256) void k_refine(
    const float* __restrict__ Zt, const float* __restrict__ cb,
    const float* __restrict__ cnorm, const _Float16* __restrict__ bmin,
    int* __restrict__ minidx, float* __restrict__ out_idx)
{
    const int m = blockIdx.x * 4 + (threadIdx.x >> 6);
    const int lane = threadIdx.x & 63;

    const _Float16* brow = bmin + (size_t)m * 1024 + lane * 16;
    const half8 u0 = *(const half8*)brow;
    const half8 u1 = *(const half8*)(brow + 8);
    float um[16];
#pragma unroll
    for (int k = 0; k < 8; ++k) { um[k] = (float)u0[k]; um[8 + k] = (float)u1[k]; }

    float g = FLT_BIG;
#pragma unroll
    for (int k = 0; k < 16; ++k) g = fminf(g, um[k]);
#pragma unroll
    for (int s = 32; s > 0; s >>= 1) g = fminf(g, __shfl_xor(g, s));
    const float thr = g + MARGIN;

    float zr[8];
#pragma unroll
    for (int j = 0; j < 8; ++j)
        zr[j] = Zt[(size_t)m * 512 + lane + 64 * j];

    float bestv = FLT_BIG; int besti = 0;

    bool any = false;
#pragma unroll
    for (int k = 0; k < 16; ++k) any |= (um[k] <= thr);
    unsigned long long mask = __ballot(any);

    while (mask) {
        const int L = __ffsll(mask) - 1;
        mask &= mask - 1;
#pragma unroll
        for (int k = 0; k < 16; ++k) {
            const float uv = __shfl(um[k], L);
            if (!(uv <= thr)) continue;
            const int nbase = (L * 16 + k) * 8;
            for (int q = 0; q < 8; q += 2) {
                const float* r0 = cb + (size_t)(nbase + q) * 512 + lane;
                const float* r1 = r0 + 512;
                float d0 = 0.f, d1 = 0.f;
#pragma unroll
                for (int j = 0; j < 8; ++j) {
                    d0 += zr[j] * r0[64 * j];
                    d1 += zr[j] * r1[64 * j];
                }
#pragma unroll
                for (int s = 32; s > 0; s >>= 1) {
                    d0 += __shfl_xor(d0, s);
                    d1 += __shfl_xor(d1, s);
                }
                const float f0 = cnorm[nbase + q]     - 2.0f * d0;
                const float f1 = cnorm[nbase + q + 1] - 2.0f * d1;
                if (f0 < bestv) { bestv = f0; besti = nbase + q; }
                if (f1 < bestv) { bestv = f1; besti = nbase + q + 1; }
            }
        }
    }
    if (lane == 0) {
        minidx[m] = besti;
        out_idx[m] = (float)besti;
    }
}

// ---------------------------------------------------------------------------
// K4: z_q gather + transpose to (B,C,T) + commit loss (finalized in-kernel).
// ---------------------------------------------------------------------------
#define ZQ_BLOCKS (4*16*8)
__global__ __launch_bounds__(256) void k_zq(
    const float* __restrict__ z, const float* __restrict__ cb,
    const int* __restrict__ minidx, float* __restrict__ outz,
    float* __restrict__ lossacc, unsigned int* __restrict__ donecnt,
    float* __restrict__ outloss)
{
    __shared__ float red[4];
    const int cc = blockIdx.x, tt = blockIdx.y, b = blockIdx.z;
    const int tl = threadIdx.x & 63;
    const int cg = threadIdx.x >> 6;
    const int t = tt * 64 + tl;
    const int idx = minidx[b * TT + t];
    const float* __restrict__ crow = cb + (size_t)idx * 512;

    float lsum = 0.f;
#pragma unroll 8
    for (int k = 0; k < 32; ++k) {
        const int c = cc * 128 + cg + k * 4;
        const float cv = crow[c];
        const size_t off = ((size_t)(b * ED + c)) * TT + t;
        const float zv = z[off];
        const float d = cv - zv;
        lsum += d * d;
        outz[off] = cv;
    }
#pragma unroll
    for (int off = 32; off > 0; off >>= 1) lsum += __shfl_down(lsum, off);
    if (tl == 0) red[threadIdx.x >> 6] = lsum;
    __syncthreads();
    if (threadIdx.x == 0) {
        atomicAdd(lossacc, red[0] + red[1] + red[2] + red[3]);
        __threadfence();
        const unsigned int old = atomicAdd(donecnt, 1u);
        if (old == ZQ_BLOCKS - 1) {
            const float total = atomicAdd(lossacc, 0.0f);
            *outloss = 1.25f * total / (float)(BB * ED * TT);
        }
    }
}

// ---------------------------------------------------------------------------
extern "C" void kernel_launch(void* const* d_in, const int* in_sizes, int n_in,
                              void* d_out, int out_size, void* d_ws, size_t ws_size,
                              hipStream_t stream)
{
    const float* z   = (const float*)d_in[0];
    const int*   dom = (const int*)d_in[1];
    const float* emb = (const float*)d_in[3];
    const float* pw  = (const float*)d_in[4];
    const float* pb  = (const float*)d_in[5];
    float* out = (float*)d_out;

    char* p = (char*)d_ws;
    _Float16* Zh = (_Float16*)p;            p += (size_t)MM * 512 * 2;   // 8 MB
    float*    Zt = (float*)p;               p += (size_t)MM * 512 * 4;   // 16 MB
    _Float16* Eb = (_Float16*)p;            p += (size_t)NE * 1024 * 2;  // 16 MB
    _Float16* Wb = (_Float16*)p;            p += (size_t)ED * 1024 * 2;  // 1 MB
    float*    cb = (float*)p;               p += (size_t)NE * 512 * 4;   // 16 MB
    _Float16* Ch = (_Float16*)p;            p += (size_t)NE * 512 * 2;   // 8 MB
    float* cnorm = (float*)p;               p += (size_t)NE * 4;         // 32 KB
    float* lossacc = (float*)p;             p += 4;                      // == cnorm[NE]
    unsigned int* donecnt = (unsigned int*)p; p += 4;
    _Float16* bmin = (_Float16*)p;          p += (size_t)MM * 1024 * 2;  // 16 MB
    int*   minidx = (int*)p;

    k_prep   <<<1024 + (NE + ED) / 2 + 9, 256, 0, stream>>>(z, emb, pw, Zh, Zt, Eb, Wb, cnorm);
    k_cb     <<<dim3(64, 8), 256, 0, stream>>>(Eb, Wb, pb, cb, Ch, cnorm);
    k_coarse <<<dim3(64, 64), 256, 0, stream>>>(Zh, Ch, cnorm, dom, bmin);
    k_refine <<<MM / 4, 256, 0, stream>>>(Zt, cb, cnorm, bmin, minidx, out + (size_t)NE * ED);
    k_zq     <<<dim3(4, 16, 8), 256, 0, stream>>>(z, cb, minidx, out, lossacc, donecnt,
                                                  out + (size_t)NE * ED + MM);
}

// Round 10
// 213.266 us; speedup vs baseline: 4.4153x; 1.0418x over previous
//
#include <hip/hip_runtime.h>
#include <math.h>

#define NE   8192
#define ED   512
#define BB   8
#define TT   1024
#define MM   (BB*TT)

#define FLT_BIG 3.402823466e38f
#define MARGIN  0.08f

typedef _Float16 half8 __attribute__((ext_vector_type(8)));
typedef _Float16 half4 __attribute__((ext_vector_type(4)));
typedef float    floatx4 __attribute__((ext_vector_type(4)));

typedef __attribute__((address_space(3))) unsigned int       lds_u32;
typedef const __attribute__((address_space(1))) unsigned int gbl_u32;

__device__ __forceinline__ void async_copy16(void* lds, const void* g) {
    __builtin_amdgcn_global_load_lds((gbl_u32*)(unsigned long long)g,
                                     (lds_u32*)(unsigned long long)lds,
                                     16, 0, 0);
}

// ---------------------------------------------------------------------------
// K0 (fused prep): blocks 0..1023 transpose z -> Zh (f16 4z) + Zt (fp32 rows);
// blocks 1024..5375 convert emb/pw -> hi/lo f16; blocks 5376..5384 zero
// cnorm/lossacc/donecnt. (bmin needs NO init: refine only reads the
// domain-valid unit slice, which valid coarse blocks always write.)
// ---------------------------------------------------------------------------
__global__ __launch_bounds__(256) void k_prep(
    const float* __restrict__ z, const float* __restrict__ emb,
    const float* __restrict__ pw, _Float16* __restrict__ Zh,
    float* __restrict__ Zt, _Float16* __restrict__ Eb,
    _Float16* __restrict__ Wb, float* __restrict__ cnorm)
{
    const int bid = blockIdx.x;
    const int tid = threadIdx.x;
    if (bid < 1024) {
        __shared__ float T[64][68];
        const int ct = bid & 7, tt = (bid >> 3) & 15, b = bid >> 7;
        const int f4 = tid & 15;
        const int c0 = tid >> 4;
#pragma unroll
        for (int r = 0; r < 4; ++r) {
            const int c = c0 + r * 16;
            const float4 v = *(const float4*)(z + ((size_t)(b * ED + ct * 64 + c)) * TT + tt * 64 + f4 * 4);
            T[f4*4+0][c] = v.x; T[f4*4+1][c] = v.y;
            T[f4*4+2][c] = v.z; T[f4*4+3][c] = v.w;
        }
        __syncthreads();
        {   // f16 hi write
            const int tl = tid >> 2, q = tid & 3;
            const size_t m = (size_t)b * TT + tt * 64 + tl;
            _Float16* outh = Zh + m * 512 + ct * 64 + q * 16;
#pragma unroll
            for (int g = 0; g < 2; ++g) {
                half8 hv;
#pragma unroll
                for (int jj = 0; jj < 8; ++jj)
                    hv[jj] = (_Float16)(4.0f * T[tl][q*16 + g*8 + jj]);
                *(half8*)(outh + g * 8) = hv;
            }
        }
        {   // fp32 transposed write
            const int tl2 = tid >> 4;
            const int c4 = (tid & 15) * 4;
#pragma unroll
            for (int it = 0; it < 4; ++it) {
                const int t_local = tl2 + it * 16;
                const float4 v = *(const float4*)&T[t_local][c4];
                *(float4*)(Zt + ((size_t)b * TT + tt * 64 + t_local) * 512 + ct * 64 + c4) = v;
            }
        }
    } else if (bid < 5376) {
        const int g = (bid - 1024) * 256 + tid;
        const int row = g >> 7, c4 = (g & 127) * 4;
        const float* src;
        _Float16* dst;
        if (row < NE) { src = emb + (size_t)row * 512;        dst = Eb + (size_t)row * 1024; }
        else          { src = pw + (size_t)(row - NE) * 512;  dst = Wb + (size_t)(row - NE) * 1024; }
        const float4 v = *(const float4*)(src + c4);
        half4 h, l;
        const float s[4] = {v.x * 64.0f, v.y * 64.0f, v.z * 64.0f, v.w * 64.0f};
#pragma unroll
        for (int j = 0; j < 4; ++j) {
            const _Float16 hh = (_Float16)s[j];
            h[j] = hh;
            l[j] = (_Float16)(s[j] - (float)hh);
        }
        *(half4*)(dst + c4) = h;
        *(half4*)(dst + 512 + c4) = l;
    } else {
        const int zidx = bid - 5376;          // 0..8
        if (zidx < 8) {
            ((float4*)cnorm)[zidx * 256 + tid] = make_float4(0.f, 0.f, 0.f, 0.f);
        } else if (tid == 0) {
            cnorm[NE] = 0.0f;                 // lossacc
            ((unsigned int*)cnorm)[NE + 1] = 0u;  // donecnt
        }
    }
}

// ---------------------------------------------------------------------------
// K1: codebook GEMM, fused-term staging (Eh,El,Wh,Wl loaded once per 64-k
// chunk; 3 hi/lo MFMA terms). 128n x 64d tiles, 256 threads, grid (64,8).
// ---------------------------------------------------------------------------
#define S_AH 0
#define S_AL 8192
#define S_BH 16384
#define S_BL 20480
__global__ __launch_bounds__(256) void k_cb(
    const _Float16* __restrict__ Eb, const _Float16* __restrict__ Wb,
    const float* __restrict__ pb, float* __restrict__ cb,
    _Float16* __restrict__ Ch, float* __restrict__ cnorm)
{
    __shared__ __align__(16) _Float16 S[24576];   // Ah(16K)|Al(16K)|Bh(8K)|Bl(8K) bytes

    const int tid = threadIdx.x;
    const int wave = tid >> 6, lane = tid & 63;
    const int n0 = blockIdx.x * 128, d0 = blockIdx.y * 64;
    const int wm = wave >> 1, wn = wave & 1;      // 2x2 waves -> 64 codes x 32 d
    const int lm = lane & 15, lq = lane >> 4;

    floatx4 acc[4][2];
#pragma unroll
    for (int i = 0; i < 4; ++i)
#pragma unroll
        for (int j = 0; j < 2; ++j) acc[i][j] = (floatx4)0.0f;

    for (int lc = 0; lc < 8; ++lc) {
        const int kc = lc * 64;
        __syncthreads();
#pragma unroll
        for (int r = 0; r < 12; ++r) {            // 48 spans of 1KB
            const int s = wave * 12 + r;
            const int row8 = lane >> 3;
            const int srcx = lane & 7;
            if (s < 16) {
                const int row = s * 8 + row8;
                const int src = srcx ^ (row & 7);
                async_copy16(&S[S_AH + s * 512], Eb + (size_t)(n0 + row) * 1024 + kc + src * 8);
            } else if (s < 32) {
                const int s2 = s - 16;
                const int row = s2 * 8 + row8;
                const int src = srcx ^ (row & 7);
                async_copy16(&S[S_AL + s2 * 512], Eb + (size_t)(n0 + row) * 1024 + 512 + kc + src * 8);
            } else if (s < 40) {
                const int s2 = s - 32;
                const int row = s2 * 8 + row8;
                const int src = srcx ^ (row & 7);
                async_copy16(&S[S_BH + s2 * 512], Wb + (size_t)(d0 + row) * 1024 + kc + src * 8);
            } else {
                const int s2 = s - 40;
                const int row = s2 * 8 + row8;
                const int src = srcx ^ (row & 7);
                async_copy16(&S[S_BL + s2 * 512], Wb + (size_t)(d0 + row) * 1024 + 512 + kc + src * 8);
            }
        }
        __syncthreads();

#pragma unroll
        for (int ks = 0; ks < 2; ++ks) {
            half8 ah[4], al[4], bh[2], bl[2];
#pragma unroll
            for (int i = 0; i < 4; ++i) {
                const int row = wm * 64 + i * 16 + lm;
                const int slot = (ks * 4 + lq) ^ (row & 7);
                ah[i] = *(const half8*)&S[S_AH + row * 64 + slot * 8];
                al[i] = *(const half8*)&S[S_AL + row * 64 + slot * 8];
            }
#pragma unroll
            for (int j = 0; j < 2; ++j) {
                const int row = wn * 32 + j * 16 + lm;
                const int slot = (ks * 4 + lq) ^ (row & 7);
                bh[j] = *(const half8*)&S[S_BH + row * 64 + slot * 8];
                bl[j] = *(const half8*)&S[S_BL + row * 64 + slot * 8];
            }
#pragma unroll
            for (int i = 0; i < 4; ++i)
#pragma unroll
                for (int j = 0; j < 2; ++j) {
                    acc[i][j] = __builtin_amdgcn_mfma_f32_16x16x32_f16(ah[i], bh[j], acc[i][j], 0, 0, 0);
                    acc[i][j] = __builtin_amdgcn_mfma_f32_16x16x32_f16(ah[i], bl[j], acc[i][j], 0, 0, 0);
                    acc[i][j] = __builtin_amdgcn_mfma_f32_16x16x32_f16(al[i], bh[j], acc[i][j], 0, 0, 0);
                }
        }
    }

    float bias[2];
#pragma unroll
    for (int j = 0; j < 2; ++j) bias[j] = pb[d0 + wn * 32 + j * 16 + lm];

    float nsum[16];
#pragma unroll
    for (int p = 0; p < 16; ++p) nsum[p] = 0.0f;

#pragma unroll
    for (int i = 0; i < 4; ++i) {
#pragma unroll
        for (int j = 0; j < 2; ++j) {
            const int d = d0 + wn * 32 + j * 16 + lm;
#pragma unroll
            for (int r = 0; r < 4; ++r) {
                const float v = acc[i][j][r] * 0.000244140625f + bias[j];  // 1/4096
                const int n = n0 + wm * 64 + i * 16 + lq * 4 + r;
                cb[(size_t)n * 512 + d] = v;
                Ch[(size_t)n * 512 + d] = (_Float16)(v * 64.0f);
                nsum[i * 4 + r] += v * v;
            }
        }
    }
#pragma unroll
    for (int stp = 1; stp < 16; stp <<= 1) {
#pragma unroll
        for (int p = 0; p < 16; ++p) nsum[p] += __shfl_xor(nsum[p], stp);
    }
    float myv = nsum[0];
#pragma unroll
    for (int p = 1; p < 16; ++p) if (lm == p) myv = nsum[p];
    const int n = n0 + wm * 64 + (lm >> 2) * 16 + lq * 4 + (lm & 3);
    atomicAdd(&cnorm[n], myv);
}

// ---------------------------------------------------------------------------
// K2: coarse distance GEMM (hi-only, K=512), codes on MFMA rows (A=Ch).
// 4-CODE units: unit-min is fully in-lane (min over the acc r-quad, no
// shuffles). bmin[m][2048] f16. Invalid blocks return WITHOUT writing
// (refine is domain-aware). bs aliases As after the K-loop (LDS stays 33KB).
// ---------------------------------------------------------------------------
__global__ __launch_bounds__(256) void k_coarse(
    const _Float16* __restrict__ Zh, const _Float16* __restrict__ Ch,
    const float* __restrict__ cnorm, const int* __restrict__ dom_arr,
    _Float16* __restrict__ bmin)
{
    const int mt = blockIdx.x;          // z-tile 0..63
    const int nt = blockIdx.y;          // code-tile 0..63
    const int b = mt >> 3;
    const int dom = dom_arr[b];
    const int chunk = nt >> 4;
    const bool valid = (dom == 3) || (dom == 0 && chunk == 0) ||
                       (dom == 1 && chunk == 1) || (dom == 2 && chunk >= 2);
    if (!valid) return;

    const int tid = threadIdx.x;
    const int m0 = mt * 128, n0 = nt * 128;

    __shared__ __align__(16) _Float16 As[128 * 64];      // codes (reused as bs)
    __shared__ __align__(16) _Float16 Bs[128 * 64];      // z
    __shared__ __align__(16) float cnLds[128];

    const int wave = tid >> 6, lane = tid & 63;
    const int wm = wave >> 1, wn = wave & 1;   // wm: code rows, wn: z cols
    const int lm = lane & 15, lq = lane >> 4;

    floatx4 acc[4][4];
#pragma unroll
    for (int i = 0; i < 4; ++i)
#pragma unroll
        for (int j = 0; j < 4; ++j) acc[i][j] = (floatx4)0.0f;

    for (int lc = 0; lc < 8; ++lc) {
        const int kk0 = lc * 64;
        __syncthreads();
#pragma unroll
        for (int r = 0; r < 4; ++r) {
            const int s = wave * 4 + r;
            const int row = s * 8 + (lane >> 3);
            const int src = (lane & 7) ^ (row & 7);
            async_copy16(&As[s * 512], Ch + (size_t)(n0 + row) * 512 + kk0 + src * 8);
            async_copy16(&Bs[s * 512], Zh + (size_t)(m0 + row) * 512 + kk0 + src * 8);
        }
        if (lc == 0 && wave == 0 && lane < 32)
            async_copy16(&cnLds[0], cnorm + n0 + lane * 4);
        __syncthreads();

#pragma unroll
        for (int ks = 0; ks < 2; ++ks) {
            half8 af[4], bf[4];
#pragma unroll
            for (int i = 0; i < 4; ++i) {
                const int row = wm * 64 + i * 16 + lm;            // code row
                const int slot = (ks * 4 + lq) ^ (row & 7);
                af[i] = *(const half8*)&As[row * 64 + slot * 8];
            }
#pragma unroll
            for (int j = 0; j < 4; ++j) {
                const int row = wn * 64 + j * 16 + lm;            // z row
                const int slot = (ks * 4 + lq) ^ (row & 7);
                bf[j] = *(const half8*)&Bs[row * 64 + slot * 8];
            }
#pragma unroll
            for (int i = 0; i < 4; ++i)
#pragma unroll
                for (int j = 0; j < 4; ++j)
                    acc[i][j] = __builtin_amdgcn_mfma_f32_16x16x32_f16(af[i], bf[j], acc[i][j], 0, 0, 0);
        }
    }

    // D layout: row (code) = wm*64 + i*16 + lq*4 + r, col (z) = wn*64 + j*16 + lm
    float cnv[4][4];
#pragma unroll
    for (int i = 0; i < 4; ++i)
#pragma unroll
        for (int r = 0; r < 4; ++r)
            cnv[i][r] = cnLds[wm * 64 + i * 16 + lq * 4 + r];

    // 4-code unit minima: fully in-lane over the r-quad
    float um[4][4];
#pragma unroll
    for (int i = 0; i < 4; ++i) {
#pragma unroll
        for (int j = 0; j < 4; ++j) {
            float m01 = fminf(cnv[i][0] - acc[i][j][0] * 0.0078125f,
                              cnv[i][1] - acc[i][j][1] * 0.0078125f);
            float m23 = fminf(cnv[i][2] - acc[i][j][2] * 0.0078125f,
                              cnv[i][3] - acc[i][j][3] * 0.0078125f);
            um[i][j] = fminf(m01, m23);
        }
    }

    __syncthreads();   // all waves done reading As before aliasing it
    _Float16 (*bs)[40] = (_Float16(*)[40])As;   // [m_local][unit 0..31]
#pragma unroll
    for (int i = 0; i < 4; ++i)
#pragma unroll
        for (int j = 0; j < 4; ++j)
            bs[wn * 64 + j * 16 + lm][wm * 16 + i * 4 + lq] = (_Float16)um[i][j];
    __syncthreads();
    {   // writeout: 128 rows x 32 units
        const int r = tid >> 1, h = tid & 1;
        half8 v0, v1;
#pragma unroll
        for (int k = 0; k < 8; ++k) { v0[k] = bs[r][h * 16 + k]; v1[k] = bs[r][h * 16 + 8 + k]; }
        _Float16* dst = bmin + (size_t)(m0 + r) * 2048 + nt * 32 + h * 16;
        *(half8*)dst = v0;
        *(half8*)(dst + 8) = v1;
    }
}

// ---------------------------------------------------------------------------
// K3: refine. One wave per z-row. Domain-aware: scans ONLY the valid unit
// slice (512/1024/2048 units of 4 codes). Exact fp32 rescoring of units
// within MARGIN of gmin; explicit tie-break to smallest index (enumeration
// order is not ascending-n here).
// ---------------------------------------------------------------------------
__global__ __launch_bounds__(256) void k_refine(
    const float* __restrict__ Zt, const float* __restrict__ cb,
    const float* __restrict__ cnorm, const _Float16* __restrict__ bmin,
    const int* __restrict__ dom_arr, int* __restrict__ minidx,
    float* __restrict__ out_idx)
{
    const int m = blockIdx.x * 4 + (threadIdx.x >> 6);
    const int lane = threadIdx.x & 63;
    const int b = m >> 10;
    const int dom = dom_arr[b];
    const int bg = (dom == 0) ? 0 : (dom == 1) ? 1 : (dom == 2) ? 2 : 0;
    const int ng = (dom == 2) ? 2 : (dom == 3) ? 4 : 1;

    const _Float16* brow = bmin + (size_t)m * 2048;
    float um[4][8];
    for (int g = 0; g < ng; ++g) {
        const half8 u = *(const half8*)(brow + (bg + g) * 512 + lane * 8);
#pragma unroll
        for (int j = 0; j < 8; ++j) um[g][j] = (float)u[j];
    }

    float gmin = FLT_BIG;
    for (int g = 0; g < ng; ++g)
#pragma unroll
        for (int j = 0; j < 8; ++j) gmin = fminf(gmin, um[g][j]);
#pragma unroll
    for (int s = 32; s > 0; s >>= 1) gmin = fminf(gmin, __shfl_xor(gmin, s));
    const float thr = gmin + MARGIN;

    float zr[8];
#pragma unroll
    for (int j = 0; j < 8; ++j)
        zr[j] = Zt[(size_t)m * 512 + lane + 64 * j];

    float bestv = FLT_BIG; int besti = 0x7FFFFFFF;

    for (int g = 0; g < ng; ++g) {
#pragma unroll
        for (int j = 0; j < 8; ++j) {
            unsigned long long mask = __ballot(um[g][j] <= thr);
            while (mask) {
                const int L = __ffsll(mask) - 1;
                mask &= mask - 1;
                const int unit = (bg + g) * 512 + L * 8 + j;
                const int nbase = unit * 4;
#pragma unroll
                for (int q = 0; q < 4; q += 2) {
                    const float* r0 = cb + (size_t)(nbase + q) * 512 + lane;
                    const float* r1 = r0 + 512;
                    float d0 = 0.f, d1 = 0.f;
#pragma unroll
                    for (int jj = 0; jj < 8; ++jj) {
                        d0 += zr[jj] * r0[64 * jj];
                        d1 += zr[jj] * r1[64 * jj];
                    }
#pragma unroll
                    for (int s = 32; s > 0; s >>= 1) {
                        d0 += __shfl_xor(d0, s);
                        d1 += __shfl_xor(d1, s);
                    }
                    const float f0 = cnorm[nbase + q]     - 2.0f * d0;
                    const float f1 = cnorm[nbase + q + 1] - 2.0f * d1;
                    const int n0i = nbase + q, n1i = nbase + q + 1;
                    if (f0 < bestv || (f0 == bestv && n0i < besti)) { bestv = f0; besti = n0i; }
                    if (f1 < bestv || (f1 == bestv && n1i < besti)) { bestv = f1; besti = n1i; }
                }
            }
        }
    }
    if (lane == 0) {
        minidx[m] = besti;
        out_idx[m] = (float)besti;
    }
}

// ---------------------------------------------------------------------------
// K4: z_q gather + transpose to (B,C,T) + commit loss (finalized in-kernel).
// ---------------------------------------------------------------------------
#define ZQ_BLOCKS (4*16*8)
__global__ __launch_bounds__(256) void k_zq(
    const float* __restrict__ z, const float* __restrict__ cb,
    const int* __restrict__ minidx, float* __restrict__ outz,
    float* __restrict__ lossacc, unsigned int* __restrict__ donecnt,
    float* __restrict__ outloss)
{
    __shared__ float red[4];
    const int cc = blockIdx.x, tt = blockIdx.y, b = blockIdx.z;
    const int tl = threadIdx.x & 63;
    const int cg = threadIdx.x >> 6;
    const int t = tt * 64 + tl;
    const int idx = minidx[b * TT + t];
    const float* __restrict__ crow = cb + (size_t)idx * 512;

    float lsum = 0.f;
#pragma unroll 8
    for (int k = 0; k < 32; ++k) {
        const int c = cc * 128 + cg + k * 4;
        const float cv = crow[c];
        const size_t off = ((size_t)(b * ED + c)) * TT + t;
        const float zv = z[off];
        const float d = cv - zv;
        lsum += d * d;
        outz[off] = cv;
    }
#pragma unroll
    for (int off = 32; off > 0; off >>= 1) lsum += __shfl_down(lsum, off);
    if (tl == 0) red[threadIdx.x >> 6] = lsum;
    __syncthreads();
    if (threadIdx.x == 0) {
        atomicAdd(lossacc, red[0] + red[1] + red[2] + red[3]);
        __threadfence();
        const unsigned int old = atomicAdd(donecnt, 1u);
        if (old == ZQ_BLOCKS - 1) {
            const float total = atomicAdd(lossacc, 0.0f);
            *outloss = 1.25f * total / (float)(BB * ED * TT);
        }
    }
}

// ---------------------------------------------------------------------------
extern "C" void kernel_launch(void* const* d_in, const int* in_sizes, int n_in,
                              void* d_out, int out_size, void* d_ws, size_t ws_size,
                              hipStream_t stream)
{
    const float* z   = (const float*)d_in[0];
    const int*   dom = (const int*)d_in[1];
    const float* emb = (const float*)d_in[3];
    const float* pw  = (const float*)d_in[4];
    const float* pb  = (const float*)d_in[5];
    float* out = (float*)d_out;

    char* p = (char*)d_ws;
    _Float16* Zh = (_Float16*)p;            p += (size_t)MM * 512 * 2;   // 8 MB
    float*    Zt = (float*)p;               p += (size_t)MM * 512 * 4;   // 16 MB
    _Float16* Eb = (_Float16*)p;            p += (size_t)NE * 1024 * 2;  // 16 MB
    _Float16* Wb = (_Float16*)p;            p += (size_t)ED * 1024 * 2;  // 1 MB
    float*    cb = (float*)p;               p += (size_t)NE * 512 * 4;   // 16 MB
    _Float16* Ch = (_Float16*)p;            p += (size_t)NE * 512 * 2;   // 8 MB
    float* cnorm = (float*)p;               p += (size_t)NE * 4;         // 32 KB
    float* lossacc = (float*)p;             p += 4;                      // == cnorm[NE]
    unsigned int* donecnt = (unsigned int*)p; p += 4;
    _Float16* bmin = (_Float16*)p;          p += (size_t)MM * 2048 * 2;  // 32 MB
    int*   minidx = (int*)p;

    k_prep   <<<1024 + (NE + ED) / 2 + 9, 256, 0, stream>>>(z, emb, pw, Zh, Zt, Eb, Wb, cnorm);
    k_cb     <<<dim3(64, 8), 256, 0, stream>>>(Eb, Wb, pb, cb, Ch, cnorm);
    k_coarse <<<dim3(64, 64), 256, 0, stream>>>(Zh, Ch, cnorm, dom, bmin);
    k_refine <<<MM / 4, 256, 0, stream>>>(Zt, cb, cnorm, bmin, dom, minidx, out + (size_t)NE * ED);
    k_zq     <<<dim3(4, 16, 8), 256, 0, stream>>>(z, cb, minidx, out, lossacc, donecnt,
                                                  out + (size_t)NE * ED + MM);
}